// Round 2
// baseline (910.373 us; speedup 1.0000x reference)
//
#include <hip/hip_runtime.h>

#define N_NODES 100000
#define N_EDGES 1600000
#define HID 64

__device__ __forceinline__ float bcastf(float v, int lane) {
    return __int_as_float(__builtin_amdgcn_readlane(__float_as_int(v), lane));
}

// h = relu(x @ preW.T + preb), x: [N,3], preW: [64,3]
__global__ void pre_kernel(const float* __restrict__ x, const float* __restrict__ W,
                           const float* __restrict__ b, float* __restrict__ h) {
    int tid = blockIdx.x * blockDim.x + threadIdx.x;
    if (tid >= N_NODES * HID) return;
    int i = tid >> 6, j = tid & 63;
    float acc = b[j];
    acc = fmaf(x[i * 3 + 0], W[j * 3 + 0], acc);
    acc = fmaf(x[i * 3 + 1], W[j * 3 + 1], acc);
    acc = fmaf(x[i * 3 + 2], W[j * 3 + 2], acc);
    h[tid] = fmaxf(acc, 0.f);
}

__global__ void hist_kernel(const int* __restrict__ dst, int* __restrict__ deg) {
    int e = blockIdx.x * blockDim.x + threadIdx.x;
    if (e < N_EDGES) atomicAdd(&deg[dst[e]], 1);
}

// per-block inclusive scan of deg -> linc, block total -> bsum
__global__ void scan_a(const int* __restrict__ deg, int* __restrict__ linc,
                       int* __restrict__ bsum) {
    __shared__ int s[256];
    int t = threadIdx.x, i = blockIdx.x * 256 + t;
    int v = (i < N_NODES) ? deg[i] : 0;
    s[t] = v;
    __syncthreads();
    for (int off = 1; off < 256; off <<= 1) {
        int add = (t >= off) ? s[t - off] : 0;
        __syncthreads();
        s[t] += add;
        __syncthreads();
    }
    if (i < N_NODES) linc[i] = s[t];
    if (t == 255) bsum[blockIdx.x] = s[255];
}

// scan of block sums -> exclusive boff; also writes rowp[N] = total edges
__global__ void scan_b(const int* __restrict__ bsum, int* __restrict__ boff, int nb,
                       int* __restrict__ rowp) {
    __shared__ int s[512];
    int t = threadIdx.x;
    int v = (t < nb) ? bsum[t] : 0;
    s[t] = v;
    __syncthreads();
    for (int off = 1; off < 512; off <<= 1) {
        int add = (t >= off) ? s[t - off] : 0;
        __syncthreads();
        s[t] += add;
        __syncthreads();
    }
    if (t < nb) boff[t] = s[t] - v;
    if (t == nb - 1) rowp[N_NODES] = s[t];
}

__global__ void scan_c(const int* __restrict__ deg, const int* __restrict__ linc,
                       const int* __restrict__ boff, int* __restrict__ rowp,
                       int* __restrict__ cursor) {
    int i = blockIdx.x * blockDim.x + threadIdx.x;
    if (i >= N_NODES) return;
    int excl = linc[i] - deg[i] + boff[i >> 8];
    rowp[i] = excl;
    cursor[i] = excl;
}

__global__ void scatter_kernel(const int* __restrict__ src, const int* __restrict__ dst,
                               int* __restrict__ cursor, int* __restrict__ ssrc) {
    int e = blockIdx.x * blockDim.x + threadIdx.x;
    if (e >= N_EDGES) return;
    int d = dst[e];
    int pos = atomicAdd(&cursor[d], 1);
    __builtin_nontemporal_store(src[e], &ssrc[pos]);
}

// Fused GraphConv layer: hout_i = relu(relW @ (sum_j h_src(j)) + relb + rootW @ h_i)
// Wave-per-node (grid-stride). relW/rootW rows held in 128 VGPRs, broadcast via
// v_readlane. Gather: 8-deep unrolled independent loads for latency hiding.
// FINAL additionally applies the post layer (64 -> 2) via shuffle reduction.
template <int FINAL>
__global__ void layer_kernel(const float* __restrict__ h, const float* __restrict__ relW,
                             const float* __restrict__ relb, const float* __restrict__ rootW,
                             const float* __restrict__ postW, const float* __restrict__ postb,
                             const int* __restrict__ rowp, const int* __restrict__ ssrc,
                             float* __restrict__ hout, float* __restrict__ out) {
    int lane = threadIdx.x & 63;
    int wave = (blockIdx.x * blockDim.x + threadIdx.x) >> 6;
    int nwaves = (gridDim.x * blockDim.x) >> 6;
    float wr[64], wo[64];
#pragma unroll
    for (int k = 0; k < 64; k++) {
        wr[k] = relW[lane * 64 + k];
        wo[k] = rootW[lane * 64 + k];
    }
    float bb = relb[lane];
    float pw0 = 0.f, pw1 = 0.f, pb0 = 0.f, pb1 = 0.f;
    if (FINAL) {
        pw0 = postW[lane];
        pw1 = postW[64 + lane];
        pb0 = postb[0];
        pb1 = postb[1];
    }
    for (int i = wave; i < N_NODES; i += nwaves) {
        int r0 = rowp[i], r1 = rowp[i + 1];
        float agg = 0.f;
        for (int base = r0; base < r1; base += 64) {
            int cnt = r1 - base;
            if (cnt > 64) cnt = 64;
            int sv = (base + lane < r1) ? ssrc[base + lane] : 0;
            int e = 0;
            for (; e + 8 <= cnt; e += 8) {
                int s0 = __builtin_amdgcn_readlane(sv, e);
                int s1 = __builtin_amdgcn_readlane(sv, e + 1);
                int s2 = __builtin_amdgcn_readlane(sv, e + 2);
                int s3 = __builtin_amdgcn_readlane(sv, e + 3);
                int s4 = __builtin_amdgcn_readlane(sv, e + 4);
                int s5 = __builtin_amdgcn_readlane(sv, e + 5);
                int s6 = __builtin_amdgcn_readlane(sv, e + 6);
                int s7 = __builtin_amdgcn_readlane(sv, e + 7);
                float v0 = h[(long)s0 * 64 + lane];
                float v1 = h[(long)s1 * 64 + lane];
                float v2 = h[(long)s2 * 64 + lane];
                float v3 = h[(long)s3 * 64 + lane];
                float v4 = h[(long)s4 * 64 + lane];
                float v5 = h[(long)s5 * 64 + lane];
                float v6 = h[(long)s6 * 64 + lane];
                float v7 = h[(long)s7 * 64 + lane];
                agg += v0; agg += v1; agg += v2; agg += v3;
                agg += v4; agg += v5; agg += v6; agg += v7;
            }
            for (; e < cnt; ++e) {
                int s0 = __builtin_amdgcn_readlane(sv, e);
                agg += h[(long)s0 * 64 + lane];
            }
        }
        float hv = h[(long)i * 64 + lane];
        float am = bb, aa = 0.f;
#pragma unroll
        for (int k = 0; k < 64; k++) {
            float ak = bcastf(agg, k);
            float hk = bcastf(hv, k);
            am = fmaf(ak, wr[k], am);
            aa = fmaf(hk, wo[k], aa);
        }
        float t = fmaxf(am + aa, 0.f);
        if (FINAL) {
            float p0 = t * pw0;
            float p1 = t * pw1;
#pragma unroll
            for (int off = 32; off >= 1; off >>= 1) {
                p0 += __shfl_xor(p0, off, 64);
                p1 += __shfl_xor(p1, off, 64);
            }
            if (lane == 0) {
                out[(long)i * 2 + 0] = fmaxf(p0 + pb0, 0.f);
                out[(long)i * 2 + 1] = fmaxf(p1 + pb1, 0.f);
            }
        } else {
            hout[(long)i * 64 + lane] = t;
        }
    }
}

extern "C" void kernel_launch(void* const* d_in, const int* in_sizes, int n_in,
                              void* d_out, int out_size, void* d_ws, size_t ws_size,
                              hipStream_t stream) {
    const float* x = (const float*)d_in[0];
    const int* esrc = (const int*)d_in[1];
    const int* edst = esrc + N_EDGES;
    const float* preW = (const float*)d_in[2];
    const float* preb = (const float*)d_in[3];
    const float* postW = (const float*)d_in[4];
    const float* postb = (const float*)d_in[5];
    const float* relW[3] = {(const float*)d_in[6], (const float*)d_in[9], (const float*)d_in[12]};
    const float* relb[3] = {(const float*)d_in[7], (const float*)d_in[10], (const float*)d_in[13]};
    const float* rootW[3] = {(const float*)d_in[8], (const float*)d_in[11], (const float*)d_in[14]};
    float* out = (float*)d_out;

    const size_t NF = (size_t)N_NODES * HID;
    char* p = (char*)d_ws;
    float* hA = (float*)p; p += NF * 4;
    float* hB = (float*)p; p += NF * 4;
    int* deg = (int*)p; p += (size_t)N_NODES * 4;
    int* rowp = (int*)p; p += (size_t)(N_NODES + 1) * 4;
    p = (char*)(((size_t)p + 255) & ~(size_t)255);
    int* cursor = (int*)p; p += (size_t)N_NODES * 4;
    int* ssrc = (int*)p; p += (size_t)N_EDGES * 4;
    int* bsum = (int*)p; p += 512 * 4;
    int* boff = (int*)p; p += 512 * 4;

    const int NB_SCAN = (N_NODES + 255) / 256;  // 391

    // --- build CSR (by dst) ---
    hipMemsetAsync(deg, 0, (size_t)N_NODES * 4, stream);
    hist_kernel<<<(N_EDGES + 255) / 256, 256, 0, stream>>>(edst, deg);
    scan_a<<<NB_SCAN, 256, 0, stream>>>(deg, cursor /*linc temp*/, bsum);
    scan_b<<<1, 512, 0, stream>>>(bsum, boff, NB_SCAN, rowp);
    scan_c<<<NB_SCAN, 256, 0, stream>>>(deg, cursor, boff, rowp, cursor);
    scatter_kernel<<<(N_EDGES + 255) / 256, 256, 0, stream>>>(esrc, edst, cursor, ssrc);

    // --- pre layer ---
    pre_kernel<<<(N_NODES * HID + 255) / 256, 256, 0, stream>>>(x, preW, preb, hA);

    const int LAYER_BLOCKS = 1024;  // 4096 waves, grid-stride over 100K nodes

    // layer 0: hA -> hB
    layer_kernel<0><<<LAYER_BLOCKS, 256, 0, stream>>>(hA, relW[0], relb[0], rootW[0],
                                                      nullptr, nullptr, rowp, ssrc, hB, nullptr);
    // layer 1: hB -> hA
    layer_kernel<0><<<LAYER_BLOCKS, 256, 0, stream>>>(hB, relW[1], relb[1], rootW[1],
                                                      nullptr, nullptr, rowp, ssrc, hA, nullptr);
    // layer 2 + post: hA -> out
    layer_kernel<1><<<LAYER_BLOCKS, 256, 0, stream>>>(hA, relW[2], relb[2], rootW[2],
                                                      postW, postb, rowp, ssrc, nullptr, out);
}

// Round 3
// 553.613 us; speedup vs baseline: 1.6444x; 1.6444x over previous
//
#include <hip/hip_runtime.h>

#define N_NODES 100000
#define N_EDGES 1600000
#define HID 64

#define BSH 8                      // bucket = dst >> 8 (256 nodes per bucket)
#define NBKT ((N_NODES + 255) / 256)  // 391
#define TILE 4096

__device__ __forceinline__ float bcastf(float v, int lane) {
    return __int_as_float(__builtin_amdgcn_readlane(__float_as_int(v), lane));
}

// h = relu(x @ preW.T + preb), x: [N,3], preW: [64,3]
__global__ void pre_kernel(const float* __restrict__ x, const float* __restrict__ W,
                           const float* __restrict__ b, float* __restrict__ h) {
    int tid = blockIdx.x * blockDim.x + threadIdx.x;
    if (tid >= N_NODES * HID) return;
    int i = tid >> 6, j = tid & 63;
    float acc = b[j];
    acc = fmaf(x[i * 3 + 0], W[j * 3 + 0], acc);
    acc = fmaf(x[i * 3 + 1], W[j * 3 + 1], acc);
    acc = fmaf(x[i * 3 + 2], W[j * 3 + 2], acc);
    h[tid] = fmaxf(acc, 0.f);
}

__global__ void hist_kernel(const int* __restrict__ dst, int* __restrict__ deg) {
    int e = blockIdx.x * blockDim.x + threadIdx.x;
    if (e < N_EDGES) atomicAdd(&deg[dst[e]], 1);
}

// per-block inclusive scan of deg -> linc, block total -> bsum
__global__ void scan_a(const int* __restrict__ deg, int* __restrict__ linc,
                       int* __restrict__ bsum) {
    __shared__ int s[256];
    int t = threadIdx.x, i = blockIdx.x * 256 + t;
    int v = (i < N_NODES) ? deg[i] : 0;
    s[t] = v;
    __syncthreads();
    for (int off = 1; off < 256; off <<= 1) {
        int add = (t >= off) ? s[t - off] : 0;
        __syncthreads();
        s[t] += add;
        __syncthreads();
    }
    if (i < N_NODES) linc[i] = s[t];
    if (t == 255) bsum[blockIdx.x] = s[255];
}

// scan of block sums -> exclusive boff; also writes rowp[N] = total edges
__global__ void scan_b(const int* __restrict__ bsum, int* __restrict__ boff, int nb,
                       int* __restrict__ rowp) {
    __shared__ int s[512];
    int t = threadIdx.x;
    int v = (t < nb) ? bsum[t] : 0;
    s[t] = v;
    __syncthreads();
    for (int off = 1; off < 512; off <<= 1) {
        int add = (t >= off) ? s[t - off] : 0;
        __syncthreads();
        s[t] += add;
        __syncthreads();
    }
    if (t < nb) boff[t] = s[t] - v;
    if (t == nb - 1) rowp[N_NODES] = s[t];
}

__global__ void scan_c(const int* __restrict__ deg, const int* __restrict__ linc,
                       const int* __restrict__ boff, int* __restrict__ rowp) {
    int i = blockIdx.x * blockDim.x + threadIdx.x;
    if (i >= N_NODES) return;
    rowp[i] = linc[i] - deg[i] + boff[i >> 8];
}

__global__ void binit_kernel(const int* __restrict__ rowp, int* __restrict__ bcur) {
    int b = blockIdx.x * blockDim.x + threadIdx.x;
    if (b < NBKT) bcur[b] = rowp[b << BSH];
}

// Pass A: bin edges by dst-bucket into contiguous bucket regions of tmp.
// LDS-staged so global writes are sequential runs, not 4B random scatter.
// packed tmp word: (dst & 255) << 17 | src   (src < 2^17)
__global__ void __launch_bounds__(512) bucket_kernel(const int* __restrict__ src,
                                                     const int* __restrict__ dst,
                                                     int* __restrict__ bcur,
                                                     unsigned int* __restrict__ tmp) {
    __shared__ unsigned long long ed[TILE];  // 32 KB staged (dst<<32 | src)
    __shared__ int cnt[NBKT], cnt2[NBKT], scnx[NBKT], gbase[NBKT];
    __shared__ int s[512];
    int tid = threadIdx.x;
    int bstart = blockIdx.x * TILE;
    int tcnt = N_EDGES - bstart;
    if (tcnt > TILE) tcnt = TILE;
    if (tcnt < 0) tcnt = 0;
    for (int b = tid; b < NBKT; b += 512) { cnt[b] = 0; cnt2[b] = 0; }
    __syncthreads();
    for (int i = tid; i < tcnt; i += 512) atomicAdd(&cnt[dst[bstart + i] >> BSH], 1);
    __syncthreads();
    s[tid] = (tid < NBKT) ? cnt[tid] : 0;
    __syncthreads();
    for (int off = 1; off < 512; off <<= 1) {
        int add = (tid >= off) ? s[tid - off] : 0;
        __syncthreads();
        s[tid] += add;
        __syncthreads();
    }
    if (tid < NBKT) {
        scnx[tid] = s[tid] - cnt[tid];
        gbase[tid] = atomicAdd(&bcur[tid], cnt[tid]);
    }
    __syncthreads();
    for (int i = tid; i < tcnt; i += 512) {
        int e = bstart + i;
        int d = dst[e], sc = src[e];
        int b = d >> BSH;
        int pos = scnx[b] + atomicAdd(&cnt2[b], 1);
        ed[pos] = ((unsigned long long)(unsigned)d << 32) | (unsigned)sc;
    }
    __syncthreads();
    for (int i = tid; i < tcnt; i += 512) {
        unsigned long long v = ed[i];
        int d = (int)(v >> 32);
        unsigned sc = (unsigned)v;
        int b = d >> BSH;
        tmp[gbase[b] + (i - scnx[b])] = ((unsigned)(d & 255) << 17) | sc;
    }
}

// Pass B: within-bucket sort by node via LDS cursors; writes land in the
// bucket's own ~L2-resident region of ssrc.
__global__ void __launch_bounds__(256) passb_kernel(const unsigned int* __restrict__ tmp,
                                                    const int* __restrict__ rowp,
                                                    int* __restrict__ ssrc) {
    __shared__ int cur[256];
    int tid = threadIdx.x;
    int nbase = blockIdx.x << BSH;
    int nidx = nbase + tid;
    cur[tid] = rowp[nidx < N_NODES ? nidx : N_NODES];
    int lo = rowp[nbase];
    int nend = nbase + 256;
    if (nend > N_NODES) nend = N_NODES;
    int hi = rowp[nend];
    __syncthreads();
    for (int i = lo + tid; i < hi; i += 256) {
        unsigned v = tmp[i];
        int dlow = v >> 17;
        int pos = atomicAdd(&cur[dlow], 1);
        ssrc[pos] = (int)(v & 0x1FFFF);
    }
}

// m = h @ relW.T ; aout = h @ rootW.T + relb.  Weights in LDS (transposed,
// conflict-free stride-1 reads), wave-per-node, h broadcast via readlane.
__global__ void __launch_bounds__(256) gemm2_kernel(const float* __restrict__ h,
                                                    const float* __restrict__ relW,
                                                    const float* __restrict__ relb,
                                                    const float* __restrict__ rootW,
                                                    float* __restrict__ m,
                                                    float* __restrict__ aout) {
    __shared__ float WT0[64 * 64];  // WT0[k*64+j] = relW[j*64+k]
    __shared__ float WT1[64 * 64];
    int tid = threadIdx.x;
    for (int idx = tid; idx < 4096; idx += 256) {
        int j = idx >> 6, k = idx & 63;
        WT0[k * 64 + j] = relW[idx];
        WT1[k * 64 + j] = rootW[idx];
    }
    __syncthreads();
    int lane = tid & 63;
    int wave = (blockIdx.x * blockDim.x + tid) >> 6;
    int nwaves = (gridDim.x * blockDim.x) >> 6;
    float bb = relb[lane];
    for (int i = wave; i < N_NODES; i += nwaves) {
        float hv = h[(long)i * 64 + lane];
        float am = 0.f, aa = 0.f;
#pragma unroll
        for (int k = 0; k < 64; k++) {
            float hk = bcastf(hv, k);
            am = fmaf(hk, WT0[k * 64 + lane], am);
            aa = fmaf(hk, WT1[k * 64 + lane], aa);
        }
        m[(long)i * 64 + lane] = am;
        aout[(long)i * 64 + lane] = aa + bb;
    }
}

// a[i] = relu(a[i] + sum_{e in CSR row i} m[ssrc[e]]) ; FINAL fuses post layer.
template <int FINAL>
__global__ void gather_kernel(const float* __restrict__ m, float* __restrict__ a,
                              const int* __restrict__ rowp, const int* __restrict__ ssrc,
                              const float* __restrict__ postW, const float* __restrict__ postb,
                              float* __restrict__ out) {
    int lane = threadIdx.x & 63;
    int node = (blockIdx.x * blockDim.x + threadIdx.x) >> 6;
    if (node >= N_NODES) return;
    int r0 = rowp[node], r1 = rowp[node + 1];
    float acc = a[(long)node * 64 + lane];
    for (int base = r0; base < r1; base += 64) {
        int cnt = r1 - base;
        if (cnt > 64) cnt = 64;
        int sv = (base + lane < r1) ? ssrc[base + lane] : 0;
        int e = 0;
        for (; e + 8 <= cnt; e += 8) {
            int s0 = __builtin_amdgcn_readlane(sv, e);
            int s1 = __builtin_amdgcn_readlane(sv, e + 1);
            int s2 = __builtin_amdgcn_readlane(sv, e + 2);
            int s3 = __builtin_amdgcn_readlane(sv, e + 3);
            int s4 = __builtin_amdgcn_readlane(sv, e + 4);
            int s5 = __builtin_amdgcn_readlane(sv, e + 5);
            int s6 = __builtin_amdgcn_readlane(sv, e + 6);
            int s7 = __builtin_amdgcn_readlane(sv, e + 7);
            float v0 = m[(long)s0 * 64 + lane];
            float v1 = m[(long)s1 * 64 + lane];
            float v2 = m[(long)s2 * 64 + lane];
            float v3 = m[(long)s3 * 64 + lane];
            float v4 = m[(long)s4 * 64 + lane];
            float v5 = m[(long)s5 * 64 + lane];
            float v6 = m[(long)s6 * 64 + lane];
            float v7 = m[(long)s7 * 64 + lane];
            acc += v0; acc += v1; acc += v2; acc += v3;
            acc += v4; acc += v5; acc += v6; acc += v7;
        }
        for (; e < cnt; ++e) {
            int s0 = __builtin_amdgcn_readlane(sv, e);
            acc += m[(long)s0 * 64 + lane];
        }
    }
    acc = fmaxf(acc, 0.f);
    if (FINAL) {
        float p0 = acc * postW[lane];
        float p1 = acc * postW[64 + lane];
#pragma unroll
        for (int off = 32; off >= 1; off >>= 1) {
            p0 += __shfl_xor(p0, off, 64);
            p1 += __shfl_xor(p1, off, 64);
        }
        if (lane == 0) {
            out[(long)node * 2 + 0] = fmaxf(p0 + postb[0], 0.f);
            out[(long)node * 2 + 1] = fmaxf(p1 + postb[1], 0.f);
        }
    } else {
        a[(long)node * 64 + lane] = acc;
    }
}

extern "C" void kernel_launch(void* const* d_in, const int* in_sizes, int n_in,
                              void* d_out, int out_size, void* d_ws, size_t ws_size,
                              hipStream_t stream) {
    const float* x = (const float*)d_in[0];
    const int* esrc = (const int*)d_in[1];
    const int* edst = esrc + N_EDGES;
    const float* preW = (const float*)d_in[2];
    const float* preb = (const float*)d_in[3];
    const float* postW = (const float*)d_in[4];
    const float* postb = (const float*)d_in[5];
    const float* relW[3] = {(const float*)d_in[6], (const float*)d_in[9], (const float*)d_in[12]};
    const float* relb[3] = {(const float*)d_in[7], (const float*)d_in[10], (const float*)d_in[13]};
    const float* rootW[3] = {(const float*)d_in[8], (const float*)d_in[11], (const float*)d_in[14]};
    float* out = (float*)d_out;

    const size_t NF = (size_t)N_NODES * HID;
    char* p = (char*)d_ws;
    float* hA = (float*)p; p += NF * 4;
    float* hB = (float*)p; p += NF * 4;
    float* mB = (float*)p; p += NF * 4;
    int* deg = (int*)p; p += (size_t)N_NODES * 4;
    int* rowp = (int*)p; p += (size_t)(N_NODES + 1) * 4;
    p = (char*)(((size_t)p + 255) & ~(size_t)255);
    int* linc = (int*)p; p += (size_t)N_NODES * 4;
    int* ssrc = (int*)p; p += (size_t)N_EDGES * 4;
    int* bsum = (int*)p; p += 512 * 4;
    int* boff = (int*)p; p += 512 * 4;
    int* bcur = (int*)p; p += 512 * 4;
    // tmp aliases mB: CSR build finishes before any gemm2 writes mB.
    unsigned int* tmp = (unsigned int*)mB;

    const int NB_SCAN = (N_NODES + 255) / 256;  // 391

    // --- build CSR (by dst): hist -> scan -> LDS-binned 2-pass counting sort ---
    hipMemsetAsync(deg, 0, (size_t)N_NODES * 4, stream);
    hist_kernel<<<(N_EDGES + 255) / 256, 256, 0, stream>>>(edst, deg);
    scan_a<<<NB_SCAN, 256, 0, stream>>>(deg, linc, bsum);
    scan_b<<<1, 512, 0, stream>>>(bsum, boff, NB_SCAN, rowp);
    scan_c<<<NB_SCAN, 256, 0, stream>>>(deg, linc, boff, rowp);
    binit_kernel<<<(NBKT + 255) / 256, 256, 0, stream>>>(rowp, bcur);
    bucket_kernel<<<(N_EDGES + TILE - 1) / TILE, 512, 0, stream>>>(esrc, edst, bcur, tmp);
    passb_kernel<<<NBKT, 256, 0, stream>>>(tmp, rowp, ssrc);

    // --- pre layer ---
    pre_kernel<<<(N_NODES * HID + 255) / 256, 256, 0, stream>>>(x, preW, preb, hA);

    const int GEMM_BLOCKS = 512;
    const int GATHER_BLOCKS = (N_NODES + 3) / 4;  // 4 waves/block, wave-per-node

    // layer 0: hA -> hB
    gemm2_kernel<<<GEMM_BLOCKS, 256, 0, stream>>>(hA, relW[0], relb[0], rootW[0], mB, hB);
    gather_kernel<0><<<GATHER_BLOCKS, 256, 0, stream>>>(mB, hB, rowp, ssrc, nullptr, nullptr, nullptr);
    // layer 1: hB -> hA
    gemm2_kernel<<<GEMM_BLOCKS, 256, 0, stream>>>(hB, relW[1], relb[1], rootW[1], mB, hA);
    gather_kernel<0><<<GATHER_BLOCKS, 256, 0, stream>>>(mB, hA, rowp, ssrc, nullptr, nullptr, nullptr);
    // layer 2 + post: hA -> out
    gemm2_kernel<<<GEMM_BLOCKS, 256, 0, stream>>>(hA, relW[2], relb[2], rootW[2], mB, hB);
    gather_kernel<1><<<GATHER_BLOCKS, 256, 0, stream>>>(mB, hB, rowp, ssrc, postW, postb, out);
}

// Round 4
// 490.886 us; speedup vs baseline: 1.8545x; 1.1278x over previous
//
#include <hip/hip_runtime.h>

#define N_NODES 100000
#define N_EDGES 1600000
#define HID 64

#define BSH 8                         // bucket = dst >> 8 (256 nodes per bucket)
#define NBKT ((N_NODES + 255) / 256)  // 391
#define TILE 4096                     // edges per bucket_kernel block
#define TILE2 8192                    // edges per bhist block

__device__ __forceinline__ float bcastf(float v, int lane) {
    return __int_as_float(__builtin_amdgcn_readlane(__float_as_int(v), lane));
}

// h = relu(x @ preW.T + preb), x: [N,3], preW: [64,3]
__global__ void pre_kernel(const float* __restrict__ x, const float* __restrict__ W,
                           const float* __restrict__ b, float* __restrict__ h) {
    int tid = blockIdx.x * blockDim.x + threadIdx.x;
    if (tid >= N_NODES * HID) return;
    int i = tid >> 6, j = tid & 63;
    float acc = b[j];
    acc = fmaf(x[i * 3 + 0], W[j * 3 + 0], acc);
    acc = fmaf(x[i * 3 + 1], W[j * 3 + 1], acc);
    acc = fmaf(x[i * 3 + 2], W[j * 3 + 2], acc);
    h[tid] = fmaxf(acc, 0.f);
}

// Per-bucket histogram, LDS-staged: ~196 blocks x <=391 global atomics.
__global__ void __launch_bounds__(512) bhist_kernel(const int* __restrict__ dst,
                                                    int* __restrict__ bcnt) {
    __shared__ int c[NBKT];
    int tid = threadIdx.x;
    for (int b = tid; b < NBKT; b += 512) c[b] = 0;
    __syncthreads();
    int start = blockIdx.x * TILE2;
    int end = start + TILE2;
    if (end > N_EDGES) end = N_EDGES;
    for (int i = start + tid; i < end; i += 512) atomicAdd(&c[dst[i] >> BSH], 1);
    __syncthreads();
    for (int b = tid; b < NBKT; b += 512)
        if (c[b]) atomicAdd(&bcnt[b], c[b]);
}

// Exclusive scan of 391 bucket counts; seeds bkt_off, bcur, rowp[N].
__global__ void __launch_bounds__(512) kscan_bkt(const int* __restrict__ bcnt,
                                                 int* __restrict__ bkt_off,
                                                 int* __restrict__ bcur,
                                                 int* __restrict__ rowp) {
    __shared__ int s[512];
    int t = threadIdx.x;
    int v = (t < NBKT) ? bcnt[t] : 0;
    s[t] = v;
    __syncthreads();
    for (int off = 1; off < 512; off <<= 1) {
        int a = (t >= off) ? s[t - off] : 0;
        __syncthreads();
        s[t] += a;
        __syncthreads();
    }
    if (t < NBKT) { bkt_off[t] = s[t] - v; bcur[t] = s[t] - v; }
    if (t == 511) { bkt_off[NBKT] = s[511]; rowp[N_NODES] = s[511]; }
}

// Pass A: bin edges by dst-bucket into contiguous bucket regions of tmp.
// LDS-staged so global writes are sequential runs, not 4B random scatter.
// packed tmp word: (dst & 255) << 17 | src   (src < 2^17)
__global__ void __launch_bounds__(512) bucket_kernel(const int* __restrict__ src,
                                                     const int* __restrict__ dst,
                                                     int* __restrict__ bcur,
                                                     unsigned int* __restrict__ tmp) {
    __shared__ unsigned long long ed[TILE];  // 32 KB staged (dst<<32 | src)
    __shared__ int cnt[NBKT], cnt2[NBKT], scnx[NBKT], gbase[NBKT];
    __shared__ int s[512];
    int tid = threadIdx.x;
    int bstart = blockIdx.x * TILE;
    int tcnt = N_EDGES - bstart;
    if (tcnt > TILE) tcnt = TILE;
    if (tcnt < 0) tcnt = 0;
    for (int b = tid; b < NBKT; b += 512) { cnt[b] = 0; cnt2[b] = 0; }
    __syncthreads();
    for (int i = tid; i < tcnt; i += 512) atomicAdd(&cnt[dst[bstart + i] >> BSH], 1);
    __syncthreads();
    s[tid] = (tid < NBKT) ? cnt[tid] : 0;
    __syncthreads();
    for (int off = 1; off < 512; off <<= 1) {
        int add = (tid >= off) ? s[tid - off] : 0;
        __syncthreads();
        s[tid] += add;
        __syncthreads();
    }
    if (tid < NBKT) {
        scnx[tid] = s[tid] - cnt[tid];
        gbase[tid] = atomicAdd(&bcur[tid], cnt[tid]);
    }
    __syncthreads();
    for (int i = tid; i < tcnt; i += 512) {
        int e = bstart + i;
        int d = dst[e], sc = src[e];
        int b = d >> BSH;
        int pos = scnx[b] + atomicAdd(&cnt2[b], 1);
        ed[pos] = ((unsigned long long)(unsigned)d << 32) | (unsigned)sc;
    }
    __syncthreads();
    for (int i = tid; i < tcnt; i += 512) {
        unsigned long long v = ed[i];
        int d = (int)(v >> 32);
        unsigned sc = (unsigned)v;
        int b = d >> BSH;
        tmp[gbase[b] + (i - scnx[b])] = ((unsigned)(d & 255) << 17) | sc;
    }
}

// Pass B: per bucket -- count node degrees in LDS, scan -> rowp, then
// within-bucket counting-sort scatter into ssrc (bucket region is L2-resident).
__global__ void __launch_bounds__(256) passb_kernel(const unsigned int* __restrict__ tmp,
                                                    const int* __restrict__ bkt_off,
                                                    int* __restrict__ rowp,
                                                    int* __restrict__ ssrc) {
    __shared__ int cnt[256], s[256], cur[256];
    int tid = threadIdx.x;
    int b = blockIdx.x;
    int lo = bkt_off[b], hi = bkt_off[b + 1];
    cnt[tid] = 0;
    __syncthreads();
    for (int i = lo + tid; i < hi; i += 256) atomicAdd(&cnt[tmp[i] >> 17], 1);
    __syncthreads();
    int v = cnt[tid];
    s[tid] = v;
    __syncthreads();
    for (int off = 1; off < 256; off <<= 1) {
        int a = (tid >= off) ? s[tid - off] : 0;
        __syncthreads();
        s[tid] += a;
        __syncthreads();
    }
    int excl = lo + s[tid] - v;
    int node = (b << BSH) + tid;
    if (node < N_NODES) rowp[node] = excl;
    cur[tid] = excl;
    __syncthreads();
    for (int i = lo + tid; i < hi; i += 256) {
        unsigned u = tmp[i];
        int pos = atomicAdd(&cur[u >> 17], 1);
        ssrc[pos] = (int)(u & 0x1FFFF);
    }
}

// m = h @ relW.T ; aout = h @ rootW.T + relb.  Weights in LDS (transposed,
// conflict-free stride-1 reads), wave-per-node, h broadcast via readlane.
__global__ void __launch_bounds__(256) gemm2_kernel(const float* __restrict__ h,
                                                    const float* __restrict__ relW,
                                                    const float* __restrict__ relb,
                                                    const float* __restrict__ rootW,
                                                    float* __restrict__ m,
                                                    float* __restrict__ aout) {
    __shared__ float WT0[64 * 64];  // WT0[k*64+j] = relW[j*64+k]
    __shared__ float WT1[64 * 64];
    int tid = threadIdx.x;
    for (int idx = tid; idx < 4096; idx += 256) {
        int j = idx >> 6, k = idx & 63;
        WT0[k * 64 + j] = relW[idx];
        WT1[k * 64 + j] = rootW[idx];
    }
    __syncthreads();
    int lane = tid & 63;
    int wave = (blockIdx.x * blockDim.x + tid) >> 6;
    int nwaves = (gridDim.x * blockDim.x) >> 6;
    float bb = relb[lane];
    for (int i = wave; i < N_NODES; i += nwaves) {
        float hv = h[(long)i * 64 + lane];
        float am = 0.f, aa = 0.f;
#pragma unroll
        for (int k = 0; k < 64; k++) {
            float hk = bcastf(hv, k);
            am = fmaf(hk, WT0[k * 64 + lane], am);
            aa = fmaf(hk, WT1[k * 64 + lane], aa);
        }
        m[(long)i * 64 + lane] = am;
        aout[(long)i * 64 + lane] = aa + bb;
    }
}

// a[i] = relu(a[i] + sum_{e in CSR row i} m[ssrc[e]]) ; FINAL fuses post layer.
template <int FINAL>
__global__ void gather_kernel(const float* __restrict__ m, float* __restrict__ a,
                              const int* __restrict__ rowp, const int* __restrict__ ssrc,
                              const float* __restrict__ postW, const float* __restrict__ postb,
                              float* __restrict__ out) {
    int lane = threadIdx.x & 63;
    int node = (blockIdx.x * blockDim.x + threadIdx.x) >> 6;
    if (node >= N_NODES) return;
    int r0 = rowp[node], r1 = rowp[node + 1];
    float acc = a[(long)node * 64 + lane];
    for (int base = r0; base < r1; base += 64) {
        int cnt = r1 - base;
        if (cnt > 64) cnt = 64;
        int sv = (base + lane < r1) ? ssrc[base + lane] : 0;
        int e = 0;
        for (; e + 8 <= cnt; e += 8) {
            int s0 = __builtin_amdgcn_readlane(sv, e);
            int s1 = __builtin_amdgcn_readlane(sv, e + 1);
            int s2 = __builtin_amdgcn_readlane(sv, e + 2);
            int s3 = __builtin_amdgcn_readlane(sv, e + 3);
            int s4 = __builtin_amdgcn_readlane(sv, e + 4);
            int s5 = __builtin_amdgcn_readlane(sv, e + 5);
            int s6 = __builtin_amdgcn_readlane(sv, e + 6);
            int s7 = __builtin_amdgcn_readlane(sv, e + 7);
            float v0 = m[(long)s0 * 64 + lane];
            float v1 = m[(long)s1 * 64 + lane];
            float v2 = m[(long)s2 * 64 + lane];
            float v3 = m[(long)s3 * 64 + lane];
            float v4 = m[(long)s4 * 64 + lane];
            float v5 = m[(long)s5 * 64 + lane];
            float v6 = m[(long)s6 * 64 + lane];
            float v7 = m[(long)s7 * 64 + lane];
            acc += v0; acc += v1; acc += v2; acc += v3;
            acc += v4; acc += v5; acc += v6; acc += v7;
        }
        for (; e < cnt; ++e) {
            int s0 = __builtin_amdgcn_readlane(sv, e);
            acc += m[(long)s0 * 64 + lane];
        }
    }
    acc = fmaxf(acc, 0.f);
    if (FINAL) {
        float p0 = acc * postW[lane];
        float p1 = acc * postW[64 + lane];
#pragma unroll
        for (int off = 32; off >= 1; off >>= 1) {
            p0 += __shfl_xor(p0, off, 64);
            p1 += __shfl_xor(p1, off, 64);
        }
        if (lane == 0) {
            out[(long)node * 2 + 0] = fmaxf(p0 + postb[0], 0.f);
            out[(long)node * 2 + 1] = fmaxf(p1 + postb[1], 0.f);
        }
    } else {
        a[(long)node * 64 + lane] = acc;
    }
}

extern "C" void kernel_launch(void* const* d_in, const int* in_sizes, int n_in,
                              void* d_out, int out_size, void* d_ws, size_t ws_size,
                              hipStream_t stream) {
    const float* x = (const float*)d_in[0];
    const int* esrc = (const int*)d_in[1];
    const int* edst = esrc + N_EDGES;
    const float* preW = (const float*)d_in[2];
    const float* preb = (const float*)d_in[3];
    const float* postW = (const float*)d_in[4];
    const float* postb = (const float*)d_in[5];
    const float* relW[3] = {(const float*)d_in[6], (const float*)d_in[9], (const float*)d_in[12]};
    const float* relb[3] = {(const float*)d_in[7], (const float*)d_in[10], (const float*)d_in[13]};
    const float* rootW[3] = {(const float*)d_in[8], (const float*)d_in[11], (const float*)d_in[14]};
    float* out = (float*)d_out;

    const size_t NF = (size_t)N_NODES * HID;
    char* p = (char*)d_ws;
    float* hA = (float*)p; p += NF * 4;
    float* hB = (float*)p; p += NF * 4;
    float* mB = (float*)p; p += NF * 4;
    int* rowp = (int*)p; p += (size_t)(N_NODES + 1) * 4;
    p = (char*)(((size_t)p + 255) & ~(size_t)255);
    int* ssrc = (int*)p; p += (size_t)N_EDGES * 4;
    int* bcnt = (int*)p; p += 512 * 4;
    int* bkt_off = (int*)p; p += 512 * 4;
    int* bcur = (int*)p; p += 512 * 4;
    // tmp aliases mB: CSR build finishes before any gemm2 writes mB.
    unsigned int* tmp = (unsigned int*)mB;

    // --- build CSR (by dst): bucket hist -> bucket scan -> pass A bin ->
    //     pass B (per-node degree + scan + scatter, all in LDS) ---
    hipMemsetAsync(bcnt, 0, 512 * 4, stream);
    bhist_kernel<<<(N_EDGES + TILE2 - 1) / TILE2, 512, 0, stream>>>(edst, bcnt);
    kscan_bkt<<<1, 512, 0, stream>>>(bcnt, bkt_off, bcur, rowp);
    bucket_kernel<<<(N_EDGES + TILE - 1) / TILE, 512, 0, stream>>>(esrc, edst, bcur, tmp);
    passb_kernel<<<NBKT, 256, 0, stream>>>(tmp, bkt_off, rowp, ssrc);

    // --- pre layer ---
    pre_kernel<<<(N_NODES * HID + 255) / 256, 256, 0, stream>>>(x, preW, preb, hA);

    const int GEMM_BLOCKS = 512;
    const int GATHER_BLOCKS = (N_NODES + 3) / 4;  // 4 waves/block, wave-per-node

    // layer 0: hA -> hB
    gemm2_kernel<<<GEMM_BLOCKS, 256, 0, stream>>>(hA, relW[0], relb[0], rootW[0], mB, hB);
    gather_kernel<0><<<GATHER_BLOCKS, 256, 0, stream>>>(mB, hB, rowp, ssrc, nullptr, nullptr, nullptr);
    // layer 1: hB -> hA
    gemm2_kernel<<<GEMM_BLOCKS, 256, 0, stream>>>(hB, relW[1], relb[1], rootW[1], mB, hA);
    gather_kernel<0><<<GATHER_BLOCKS, 256, 0, stream>>>(mB, hA, rowp, ssrc, nullptr, nullptr, nullptr);
    // layer 2 + post: hA -> out
    gemm2_kernel<<<GEMM_BLOCKS, 256, 0, stream>>>(hA, relW[2], relb[2], rootW[2], mB, hB);
    gather_kernel<1><<<GATHER_BLOCKS, 256, 0, stream>>>(mB, hB, rowp, ssrc, postW, postb, out);
}

// Round 5
// 418.689 us; speedup vs baseline: 2.1743x; 1.1724x over previous
//
#include <hip/hip_runtime.h>

#define N_NODES 100000
#define N_EDGES 1600000
#define HID 64

#define BSH 8                         // bucket = dst >> 8 (256 nodes per bucket)
#define NBKT ((N_NODES + 255) / 256)  // 391
#define TILE 4096                     // edges per bucket_kernel block
#define TILE2 8192                    // edges per bhist block

// h = relu(x @ preW.T + preb), x: [N,3], preW: [64,3]
__global__ void pre_kernel(const float* __restrict__ x, const float* __restrict__ W,
                           const float* __restrict__ b, float* __restrict__ h) {
    int tid = blockIdx.x * blockDim.x + threadIdx.x;
    if (tid >= N_NODES * HID) return;
    int i = tid >> 6, j = tid & 63;
    float acc = b[j];
    acc = fmaf(x[i * 3 + 0], W[j * 3 + 0], acc);
    acc = fmaf(x[i * 3 + 1], W[j * 3 + 1], acc);
    acc = fmaf(x[i * 3 + 2], W[j * 3 + 2], acc);
    h[tid] = fmaxf(acc, 0.f);
}

// Per-bucket histogram, LDS-staged.
__global__ void __launch_bounds__(512) bhist_kernel(const int* __restrict__ dst,
                                                    int* __restrict__ bcnt) {
    __shared__ int c[NBKT];
    int tid = threadIdx.x;
    for (int b = tid; b < NBKT; b += 512) c[b] = 0;
    __syncthreads();
    int start = blockIdx.x * TILE2;
    int end = start + TILE2;
    if (end > N_EDGES) end = N_EDGES;
    for (int i = start + tid; i < end; i += 512) atomicAdd(&c[dst[i] >> BSH], 1);
    __syncthreads();
    for (int b = tid; b < NBKT; b += 512)
        if (c[b]) atomicAdd(&bcnt[b], c[b]);
}

// Exclusive scan of 391 bucket counts; seeds bkt_off, bcur, rowp[N].
__global__ void __launch_bounds__(512) kscan_bkt(const int* __restrict__ bcnt,
                                                 int* __restrict__ bkt_off,
                                                 int* __restrict__ bcur,
                                                 int* __restrict__ rowp) {
    __shared__ int s[512];
    int t = threadIdx.x;
    int v = (t < NBKT) ? bcnt[t] : 0;
    s[t] = v;
    __syncthreads();
    for (int off = 1; off < 512; off <<= 1) {
        int a = (t >= off) ? s[t - off] : 0;
        __syncthreads();
        s[t] += a;
        __syncthreads();
    }
    if (t < NBKT) { bkt_off[t] = s[t] - v; bcur[t] = s[t] - v; }
    if (t == 511) { bkt_off[NBKT] = s[511]; rowp[N_NODES] = s[511]; }
}

// Pass A: bin edges by dst-bucket into contiguous bucket regions of tmp.
// packed tmp word: (dst & 255) << 17 | src   (src < 2^17)
__global__ void __launch_bounds__(512) bucket_kernel(const int* __restrict__ src,
                                                     const int* __restrict__ dst,
                                                     int* __restrict__ bcur,
                                                     unsigned int* __restrict__ tmp) {
    __shared__ unsigned long long ed[TILE];  // 32 KB staged (dst<<32 | src)
    __shared__ int cnt[NBKT], cnt2[NBKT], scnx[NBKT], gbase[NBKT];
    __shared__ int s[512];
    int tid = threadIdx.x;
    int bstart = blockIdx.x * TILE;
    int tcnt = N_EDGES - bstart;
    if (tcnt > TILE) tcnt = TILE;
    if (tcnt < 0) tcnt = 0;
    for (int b = tid; b < NBKT; b += 512) { cnt[b] = 0; cnt2[b] = 0; }
    __syncthreads();
    for (int i = tid; i < tcnt; i += 512) atomicAdd(&cnt[dst[bstart + i] >> BSH], 1);
    __syncthreads();
    s[tid] = (tid < NBKT) ? cnt[tid] : 0;
    __syncthreads();
    for (int off = 1; off < 512; off <<= 1) {
        int add = (tid >= off) ? s[tid - off] : 0;
        __syncthreads();
        s[tid] += add;
        __syncthreads();
    }
    if (tid < NBKT) {
        scnx[tid] = s[tid] - cnt[tid];
        gbase[tid] = atomicAdd(&bcur[tid], cnt[tid]);
    }
    __syncthreads();
    for (int i = tid; i < tcnt; i += 512) {
        int e = bstart + i;
        int d = dst[e], sc = src[e];
        int b = d >> BSH;
        int pos = scnx[b] + atomicAdd(&cnt2[b], 1);
        ed[pos] = ((unsigned long long)(unsigned)d << 32) | (unsigned)sc;
    }
    __syncthreads();
    for (int i = tid; i < tcnt; i += 512) {
        unsigned long long v = ed[i];
        int d = (int)(v >> 32);
        unsigned sc = (unsigned)v;
        int b = d >> BSH;
        tmp[gbase[b] + (i - scnx[b])] = ((unsigned)(d & 255) << 17) | sc;
    }
}

// Pass B: per bucket -- node degrees in LDS, scan -> rowp, counting-sort scatter.
__global__ void __launch_bounds__(256) passb_kernel(const unsigned int* __restrict__ tmp,
                                                    const int* __restrict__ bkt_off,
                                                    int* __restrict__ rowp,
                                                    int* __restrict__ ssrc) {
    __shared__ int cnt[256], s[256], cur[256];
    int tid = threadIdx.x;
    int b = blockIdx.x;
    int lo = bkt_off[b], hi = bkt_off[b + 1];
    cnt[tid] = 0;
    __syncthreads();
    for (int i = lo + tid; i < hi; i += 256) atomicAdd(&cnt[tmp[i] >> 17], 1);
    __syncthreads();
    int v = cnt[tid];
    s[tid] = v;
    __syncthreads();
    for (int off = 1; off < 256; off <<= 1) {
        int a = (tid >= off) ? s[tid - off] : 0;
        __syncthreads();
        s[tid] += a;
        __syncthreads();
    }
    int excl = lo + s[tid] - v;
    int node = (b << BSH) + tid;
    if (node < N_NODES) rowp[node] = excl;
    cur[tid] = excl;
    __syncthreads();
    for (int i = lo + tid; i < hi; i += 256) {
        unsigned u = tmp[i];
        int pos = atomicAdd(&cur[u >> 17], 1);
        ssrc[pos] = (int)(u & 0x1FFFF);
    }
}

// Register-tiled dual GEMM: m = h @ relW.T, aout = h @ rootW.T + relb.
// Block tile: 128 nodes x 128 outputs (j<64 -> m, j>=64 -> aout).
// 256 threads, each 8 nodes x 8 outputs, LDS stride 68 (bank-conflict-free).
__global__ void __launch_bounds__(256) gemmt_kernel(const float* __restrict__ h,
                                                    const float* __restrict__ relW,
                                                    const float* __restrict__ relb,
                                                    const float* __restrict__ rootW,
                                                    float* __restrict__ m,
                                                    float* __restrict__ aout) {
    __shared__ float hs[128 * 68];
    __shared__ float ws[128 * 68];
    int tid = threadIdx.x;
    int i0 = blockIdx.x * 128;
    // stage h tile (zeros past N) and Wcat, float4
    for (int c = 0; c < 8; c++) {
        int f = tid + c * 256;            // float4 index, 2048 total
        int row = f >> 4, c4 = (f & 15) << 2;
        float4 hv = {0.f, 0.f, 0.f, 0.f};
        if (i0 + row < N_NODES) hv = *(const float4*)&h[(long)(i0 + row) * 64 + c4];
        *(float4*)&hs[row * 68 + c4] = hv;
        int j = f >> 4;
        float4 wv = (j < 64) ? *(const float4*)&relW[j * 64 + c4]
                             : *(const float4*)&rootW[(j - 64) * 64 + c4];
        *(float4*)&ws[j * 68 + c4] = wv;
    }
    int ig = tid >> 4;   // node group 0..15, nodes ig+16n
    int jg = tid & 15;   // out group 0..15,  outs  jg+16m
    float rb[4];
#pragma unroll
    for (int t = 0; t < 4; t++) rb[t] = relb[jg + 16 * t];
    float acc[8][8];
#pragma unroll
    for (int n = 0; n < 8; n++)
#pragma unroll
        for (int mm = 0; mm < 8; mm++) acc[n][mm] = 0.f;
    __syncthreads();

    for (int kk = 0; kk < 64; kk += 4) {
        float4 av[8], bv[8];
#pragma unroll
        for (int n = 0; n < 8; n++) av[n] = *(const float4*)&hs[(ig + 16 * n) * 68 + kk];
#pragma unroll
        for (int mm = 0; mm < 8; mm++) bv[mm] = *(const float4*)&ws[(jg + 16 * mm) * 68 + kk];
#pragma unroll
        for (int n = 0; n < 8; n++)
#pragma unroll
            for (int mm = 0; mm < 8; mm++) {
                acc[n][mm] = fmaf(av[n].x, bv[mm].x, acc[n][mm]);
                acc[n][mm] = fmaf(av[n].y, bv[mm].y, acc[n][mm]);
                acc[n][mm] = fmaf(av[n].z, bv[mm].z, acc[n][mm]);
                acc[n][mm] = fmaf(av[n].w, bv[mm].w, acc[n][mm]);
            }
    }
#pragma unroll
    for (int n = 0; n < 8; n++) {
        int node = i0 + ig + 16 * n;
        if (node >= N_NODES) continue;
#pragma unroll
        for (int mm = 0; mm < 4; mm++)
            m[(long)node * 64 + jg + 16 * mm] = acc[n][mm];
#pragma unroll
        for (int mm = 4; mm < 8; mm++)
            aout[(long)node * 64 + jg + 16 * (mm - 4)] = acc[n][mm] + rb[mm - 4];
    }
}

// float4-lane gather: wave per node; lane = (edge subgroup g = lane/16) x
// (feature quad f4 = (lane&15)*4). 4 edges per load instr, 1 KB/instr.
template <int FINAL>
__global__ void gather_kernel(const float* __restrict__ m, float* __restrict__ a,
                              const int* __restrict__ rowp, const int* __restrict__ ssrc,
                              const float* __restrict__ postW, const float* __restrict__ postb,
                              float* __restrict__ out) {
    int lane = threadIdx.x & 63;
    int node = (blockIdx.x * blockDim.x + threadIdx.x) >> 6;
    if (node >= N_NODES) return;
    int g = lane >> 4;
    int f4 = (lane & 15) << 2;
    int r0 = rowp[node], r1 = rowp[node + 1];
    float ax = 0.f, ay = 0.f, az = 0.f, aw = 0.f;
    for (int base = r0; base < r1; base += 64) {
        int cnt = r1 - base;
        if (cnt > 64) cnt = 64;
        int sv = (base + lane < r1) ? ssrc[base + lane] : 0;
        int nq = cnt >> 2;
        int q = 0;
        for (; q + 4 <= nq; q += 4) {
            int s0 = __shfl(sv, (q + 0) * 4 + g, 64);
            int s1 = __shfl(sv, (q + 1) * 4 + g, 64);
            int s2 = __shfl(sv, (q + 2) * 4 + g, 64);
            int s3 = __shfl(sv, (q + 3) * 4 + g, 64);
            float4 v0 = *(const float4*)(m + (long)s0 * 64 + f4);
            float4 v1 = *(const float4*)(m + (long)s1 * 64 + f4);
            float4 v2 = *(const float4*)(m + (long)s2 * 64 + f4);
            float4 v3 = *(const float4*)(m + (long)s3 * 64 + f4);
            ax += v0.x; ay += v0.y; az += v0.z; aw += v0.w;
            ax += v1.x; ay += v1.y; az += v1.z; aw += v1.w;
            ax += v2.x; ay += v2.y; az += v2.z; aw += v2.w;
            ax += v3.x; ay += v3.y; az += v3.z; aw += v3.w;
        }
        for (; q < nq; ++q) {
            int s0 = __shfl(sv, q * 4 + g, 64);
            float4 v0 = *(const float4*)(m + (long)s0 * 64 + f4);
            ax += v0.x; ay += v0.y; az += v0.z; aw += v0.w;
        }
        int rem = cnt & 3;
        if (rem) {
            int s0 = __shfl(sv, nq * 4 + g, 64);  // sv=0 for invalid lanes -> safe addr
            float4 v0 = *(const float4*)(m + (long)s0 * 64 + f4);
            if (g < rem) { ax += v0.x; ay += v0.y; az += v0.z; aw += v0.w; }
        }
    }
    // reduce across the 4 edge subgroups (after this, all lanes replicated)
    ax += __shfl_xor(ax, 16, 64); ay += __shfl_xor(ay, 16, 64);
    az += __shfl_xor(az, 16, 64); aw += __shfl_xor(aw, 16, 64);
    ax += __shfl_xor(ax, 32, 64); ay += __shfl_xor(ay, 32, 64);
    az += __shfl_xor(az, 32, 64); aw += __shfl_xor(aw, 32, 64);
    // add root term + bias, relu
    float4 ao = *(const float4*)(a + (long)node * 64 + f4);
    ax = fmaxf(ax + ao.x, 0.f); ay = fmaxf(ay + ao.y, 0.f);
    az = fmaxf(az + ao.z, 0.f); aw = fmaxf(aw + ao.w, 0.f);
    if (FINAL) {
        float4 p0w = *(const float4*)(postW + f4);
        float4 p1w = *(const float4*)(postW + 64 + f4);
        float p0 = ax * p0w.x + ay * p0w.y + az * p0w.z + aw * p0w.w;
        float p1 = ax * p1w.x + ay * p1w.y + az * p1w.z + aw * p1w.w;
#pragma unroll
        for (int off = 8; off >= 1; off >>= 1) {
            p0 += __shfl_xor(p0, off, 64);
            p1 += __shfl_xor(p1, off, 64);
        }
        if (lane == 0) {
            out[(long)node * 2 + 0] = fmaxf(p0 + postb[0], 0.f);
            out[(long)node * 2 + 1] = fmaxf(p1 + postb[1], 0.f);
        }
    } else {
        if (g == 0) {
            float4 r; r.x = ax; r.y = ay; r.z = az; r.w = aw;
            *(float4*)(a + (long)node * 64 + f4) = r;
        }
    }
}

extern "C" void kernel_launch(void* const* d_in, const int* in_sizes, int n_in,
                              void* d_out, int out_size, void* d_ws, size_t ws_size,
                              hipStream_t stream) {
    const float* x = (const float*)d_in[0];
    const int* esrc = (const int*)d_in[1];
    const int* edst = esrc + N_EDGES;
    const float* preW = (const float*)d_in[2];
    const float* preb = (const float*)d_in[3];
    const float* postW = (const float*)d_in[4];
    const float* postb = (const float*)d_in[5];
    const float* relW[3] = {(const float*)d_in[6], (const float*)d_in[9], (const float*)d_in[12]};
    const float* relb[3] = {(const float*)d_in[7], (const float*)d_in[10], (const float*)d_in[13]};
    const float* rootW[3] = {(const float*)d_in[8], (const float*)d_in[11], (const float*)d_in[14]};
    float* out = (float*)d_out;

    const size_t NF = (size_t)N_NODES * HID;
    char* p = (char*)d_ws;
    float* hA = (float*)p; p += NF * 4;
    float* hB = (float*)p; p += NF * 4;
    float* mB = (float*)p; p += NF * 4;
    int* rowp = (int*)p; p += (size_t)(N_NODES + 1) * 4;
    p = (char*)(((size_t)p + 255) & ~(size_t)255);
    int* ssrc = (int*)p; p += (size_t)N_EDGES * 4;
    int* bcnt = (int*)p; p += 512 * 4;
    int* bkt_off = (int*)p; p += 512 * 4;
    int* bcur = (int*)p; p += 512 * 4;
    // tmp aliases mB: CSR build finishes before any gemm writes mB.
    unsigned int* tmp = (unsigned int*)mB;

    // --- build CSR (by dst) ---
    hipMemsetAsync(bcnt, 0, 512 * 4, stream);
    bhist_kernel<<<(N_EDGES + TILE2 - 1) / TILE2, 512, 0, stream>>>(edst, bcnt);
    kscan_bkt<<<1, 512, 0, stream>>>(bcnt, bkt_off, bcur, rowp);
    bucket_kernel<<<(N_EDGES + TILE - 1) / TILE, 512, 0, stream>>>(esrc, edst, bcur, tmp);
    passb_kernel<<<NBKT, 256, 0, stream>>>(tmp, bkt_off, rowp, ssrc);

    // --- pre layer ---
    pre_kernel<<<(N_NODES * HID + 255) / 256, 256, 0, stream>>>(x, preW, preb, hA);

    const int GEMM_BLOCKS = (N_NODES + 127) / 128;  // 782
    const int GATHER_BLOCKS = (N_NODES + 3) / 4;    // 4 waves/block, wave-per-node

    // layer 0: hA -> hB
    gemmt_kernel<<<GEMM_BLOCKS, 256, 0, stream>>>(hA, relW[0], relb[0], rootW[0], mB, hB);
    gather_kernel<0><<<GATHER_BLOCKS, 256, 0, stream>>>(mB, hB, rowp, ssrc, nullptr, nullptr, nullptr);
    // layer 1: hB -> hA
    gemmt_kernel<<<GEMM_BLOCKS, 256, 0, stream>>>(hB, relW[1], relb[1], rootW[1], mB, hA);
    gather_kernel<0><<<GATHER_BLOCKS, 256, 0, stream>>>(mB, hA, rowp, ssrc, nullptr, nullptr, nullptr);
    // layer 2 + post: hA -> out
    gemmt_kernel<<<GEMM_BLOCKS, 256, 0, stream>>>(hA, relW[2], relb[2], rootW[2], mB, hB);
    gather_kernel<1><<<GATHER_BLOCKS, 256, 0, stream>>>(mB, hB, rowp, ssrc, postW, postb, out);
}

// Round 6
// 362.644 us; speedup vs baseline: 2.5104x; 1.1545x over previous
//
#include <hip/hip_runtime.h>
#include <hip/hip_fp16.h>

#define N_NODES 100000
#define N_EDGES 1600000
#define HID 64

#define BSH 8                         // bucket = dst >> 8 (256 nodes per bucket)
#define NBKT ((N_NODES + 255) / 256)  // 391
#define CAP 6144                      // fixed tmp region per bucket (mean 4093, sd 64)
#define TILE 4096                     // edges per bucket_kernel block

// h = relu(x @ preW.T + preb), x: [N,3], preW: [64,3]
__global__ void pre_kernel(const float* __restrict__ x, const float* __restrict__ W,
                           const float* __restrict__ b, float* __restrict__ h) {
    int tid = blockIdx.x * blockDim.x + threadIdx.x;
    if (tid >= N_NODES * HID) return;
    int i = tid >> 6, j = tid & 63;
    float acc = b[j];
    acc = fmaf(x[i * 3 + 0], W[j * 3 + 0], acc);
    acc = fmaf(x[i * 3 + 1], W[j * 3 + 1], acc);
    acc = fmaf(x[i * 3 + 2], W[j * 3 + 2], acc);
    h[tid] = fmaxf(acc, 0.f);
}

__global__ void binit_kernel(int* __restrict__ bcur) {
    int b = threadIdx.x;
    if (b < NBKT) bcur[b] = b * CAP;
}

// Pass A: bin edges by dst-bucket into fixed-capacity bucket regions of tmp.
// packed tmp word: (dst & 255) << 17 | src   (src < 2^17)
__global__ void __launch_bounds__(512) bucket_kernel(const int* __restrict__ src,
                                                     const int* __restrict__ dst,
                                                     int* __restrict__ bcur,
                                                     unsigned int* __restrict__ tmp) {
    __shared__ unsigned long long ed[TILE];  // 32 KB staged (dst<<32 | src)
    __shared__ int cnt[NBKT], cnt2[NBKT], scnx[NBKT], gbase[NBKT];
    __shared__ int s[512];
    int tid = threadIdx.x;
    int bstart = blockIdx.x * TILE;
    int tcnt = N_EDGES - bstart;
    if (tcnt > TILE) tcnt = TILE;
    if (tcnt < 0) tcnt = 0;
    for (int b = tid; b < NBKT; b += 512) { cnt[b] = 0; cnt2[b] = 0; }
    __syncthreads();
    for (int i = tid; i < tcnt; i += 512) atomicAdd(&cnt[dst[bstart + i] >> BSH], 1);
    __syncthreads();
    s[tid] = (tid < NBKT) ? cnt[tid] : 0;
    __syncthreads();
    for (int off = 1; off < 512; off <<= 1) {
        int add = (tid >= off) ? s[tid - off] : 0;
        __syncthreads();
        s[tid] += add;
        __syncthreads();
    }
    if (tid < NBKT) {
        scnx[tid] = s[tid] - cnt[tid];
        gbase[tid] = atomicAdd(&bcur[tid], cnt[tid]);
    }
    __syncthreads();
    for (int i = tid; i < tcnt; i += 512) {
        int e = bstart + i;
        int d = dst[e], sc = src[e];
        int b = d >> BSH;
        int pos = scnx[b] + atomicAdd(&cnt2[b], 1);
        ed[pos] = ((unsigned long long)(unsigned)d << 32) | (unsigned)sc;
    }
    __syncthreads();
    for (int i = tid; i < tcnt; i += 512) {
        unsigned long long v = ed[i];
        int d = (int)(v >> 32);
        unsigned sc = (unsigned)v;
        int b = d >> BSH;
        int idx = gbase[b] + (i - scnx[b]);
        if (idx < (b + 1) * CAP)  // statistically unreachable guard
            tmp[idx] = ((unsigned)(d & 255) << 17) | sc;
    }
}

// Scan of per-bucket counts (bcur - base) -> global bucket offsets; rowp[N]=total.
__global__ void __launch_bounds__(512) kscan_bkt(const int* __restrict__ bcur,
                                                 int* __restrict__ bkt_off,
                                                 int* __restrict__ rowp) {
    __shared__ int s[512];
    int t = threadIdx.x;
    int v = 0;
    if (t < NBKT) {
        v = bcur[t] - t * CAP;
        if (v > CAP) v = CAP;
    }
    s[t] = v;
    __syncthreads();
    for (int off = 1; off < 512; off <<= 1) {
        int a = (t >= off) ? s[t - off] : 0;
        __syncthreads();
        s[t] += a;
        __syncthreads();
    }
    if (t < NBKT) bkt_off[t] = s[t] - v;
    if (t == 511) { bkt_off[NBKT] = s[511]; rowp[N_NODES] = s[511]; }
}

// Pass B: per bucket -- node degrees in LDS, scan -> rowp, counting-sort scatter.
__global__ void __launch_bounds__(256) passb_kernel(const unsigned int* __restrict__ tmp,
                                                    const int* __restrict__ bkt_off,
                                                    int* __restrict__ rowp,
                                                    int* __restrict__ ssrc) {
    __shared__ int cnt[256], s[256], cur[256];
    int tid = threadIdx.x;
    int b = blockIdx.x;
    int lo_t = b * CAP;
    int ne = bkt_off[b + 1] - bkt_off[b];
    cnt[tid] = 0;
    __syncthreads();
    for (int i = tid; i < ne; i += 256) atomicAdd(&cnt[tmp[lo_t + i] >> 17], 1);
    __syncthreads();
    int v = cnt[tid];
    s[tid] = v;
    __syncthreads();
    for (int off = 1; off < 256; off <<= 1) {
        int a = (tid >= off) ? s[tid - off] : 0;
        __syncthreads();
        s[tid] += a;
        __syncthreads();
    }
    int excl = bkt_off[b] + s[tid] - v;
    int node = (b << BSH) + tid;
    if (node < N_NODES) rowp[node] = excl;
    cur[tid] = excl;
    __syncthreads();
    for (int i = tid; i < ne; i += 256) {
        unsigned u = tmp[lo_t + i];
        int pos = atomicAdd(&cur[u >> 17], 1);
        ssrc[pos] = (int)(u & 0x1FFFF);
    }
}

// Register-tiled dual GEMM: m = fp16(h @ relW.T), aout = h @ rootW.T + relb.
// Block tile: 128 nodes x 128 outputs (j<64 -> m, j>=64 -> aout).
// 256 threads, each 8 nodes x 8 outputs, LDS stride 68 (bank-conflict-free).
__global__ void __launch_bounds__(256) gemmt_kernel(const float* __restrict__ h,
                                                    const float* __restrict__ relW,
                                                    const float* __restrict__ relb,
                                                    const float* __restrict__ rootW,
                                                    __half* __restrict__ m,
                                                    float* __restrict__ aout) {
    __shared__ float hs[128 * 68];
    __shared__ float ws[128 * 68];
    int tid = threadIdx.x;
    int i0 = blockIdx.x * 128;
    for (int c = 0; c < 8; c++) {
        int f = tid + c * 256;            // float4 index, 2048 total
        int row = f >> 4, c4 = (f & 15) << 2;
        float4 hv = {0.f, 0.f, 0.f, 0.f};
        if (i0 + row < N_NODES) hv = *(const float4*)&h[(long)(i0 + row) * 64 + c4];
        *(float4*)&hs[row * 68 + c4] = hv;
        int j = f >> 4;
        float4 wv = (j < 64) ? *(const float4*)&relW[j * 64 + c4]
                             : *(const float4*)&rootW[(j - 64) * 64 + c4];
        *(float4*)&ws[j * 68 + c4] = wv;
    }
    int ig = tid >> 4;   // node group 0..15, nodes ig+16n
    int jg = tid & 15;   // out group 0..15,  outs  jg+16m
    float rb[4];
#pragma unroll
    for (int t = 0; t < 4; t++) rb[t] = relb[jg + 16 * t];
    float acc[8][8];
#pragma unroll
    for (int n = 0; n < 8; n++)
#pragma unroll
        for (int mm = 0; mm < 8; mm++) acc[n][mm] = 0.f;
    __syncthreads();

    for (int kk = 0; kk < 64; kk += 4) {
        float4 av[8], bv[8];
#pragma unroll
        for (int n = 0; n < 8; n++) av[n] = *(const float4*)&hs[(ig + 16 * n) * 68 + kk];
#pragma unroll
        for (int mm = 0; mm < 8; mm++) bv[mm] = *(const float4*)&ws[(jg + 16 * mm) * 68 + kk];
#pragma unroll
        for (int n = 0; n < 8; n++)
#pragma unroll
            for (int mm = 0; mm < 8; mm++) {
                acc[n][mm] = fmaf(av[n].x, bv[mm].x, acc[n][mm]);
                acc[n][mm] = fmaf(av[n].y, bv[mm].y, acc[n][mm]);
                acc[n][mm] = fmaf(av[n].z, bv[mm].z, acc[n][mm]);
                acc[n][mm] = fmaf(av[n].w, bv[mm].w, acc[n][mm]);
            }
    }
#pragma unroll
    for (int n = 0; n < 8; n++) {
        int node = i0 + ig + 16 * n;
        if (node >= N_NODES) continue;
#pragma unroll
        for (int mm = 0; mm < 4; mm++)
            m[(long)node * 64 + jg + 16 * mm] = __float2half(acc[n][mm]);
#pragma unroll
        for (int mm = 4; mm < 8; mm++)
            aout[(long)node * 64 + jg + 16 * (mm - 4)] = acc[n][mm] + rb[mm - 4];
    }
}

// fp16 gather: wave per node; lane = (edge subgroup g = lane>>3) x
// (feature oct f8 = (lane&7)*8). 8 edges per uint4 load, 1 KB/instr.
template <int FINAL>
__global__ void gather_kernel(const __half* __restrict__ m, float* __restrict__ a,
                              const int* __restrict__ rowp, const int* __restrict__ ssrc,
                              const float* __restrict__ postW, const float* __restrict__ postb,
                              float* __restrict__ out) {
    int lane = threadIdx.x & 63;
    int node = (blockIdx.x * blockDim.x + threadIdx.x) >> 6;
    if (node >= N_NODES) return;
    int g = lane >> 3;          // edge subgroup 0..7
    int f8 = (lane & 7) << 3;   // feature base 0,8,...,56
    int r0 = rowp[node], r1 = rowp[node + 1];
    float a0 = 0.f, a1 = 0.f, a2 = 0.f, a3 = 0.f, a4 = 0.f, a5 = 0.f, a6 = 0.f, a7 = 0.f;
#define ACC8(u)                                                       \
    {                                                                 \
        float2 f_;                                                    \
        f_ = __half22float2(*(__half2*)&(u).x); a0 += f_.x; a1 += f_.y; \
        f_ = __half22float2(*(__half2*)&(u).y); a2 += f_.x; a3 += f_.y; \
        f_ = __half22float2(*(__half2*)&(u).z); a4 += f_.x; a5 += f_.y; \
        f_ = __half22float2(*(__half2*)&(u).w); a6 += f_.x; a7 += f_.y; \
    }
    for (int base = r0; base < r1; base += 64) {
        int cnt = r1 - base;
        if (cnt > 64) cnt = 64;
        int sv = (base + lane < r1) ? ssrc[base + lane] : 0;
        int ns = cnt >> 3;
        int q = 0;
        for (; q + 4 <= ns; q += 4) {
            int s0 = __shfl(sv, (q + 0) * 8 + g, 64);
            int s1 = __shfl(sv, (q + 1) * 8 + g, 64);
            int s2 = __shfl(sv, (q + 2) * 8 + g, 64);
            int s3 = __shfl(sv, (q + 3) * 8 + g, 64);
            uint4 u0 = *(const uint4*)(m + (long)s0 * 64 + f8);
            uint4 u1 = *(const uint4*)(m + (long)s1 * 64 + f8);
            uint4 u2 = *(const uint4*)(m + (long)s2 * 64 + f8);
            uint4 u3 = *(const uint4*)(m + (long)s3 * 64 + f8);
            ACC8(u0); ACC8(u1); ACC8(u2); ACC8(u3);
        }
        for (; q < ns; ++q) {
            int s0 = __shfl(sv, q * 8 + g, 64);
            uint4 u0 = *(const uint4*)(m + (long)s0 * 64 + f8);
            ACC8(u0);
        }
        int rem = cnt & 7;
        if (rem) {
            int s0 = __shfl(sv, ns * 8 + g, 64);  // sv=0 on invalid lanes -> safe addr
            uint4 u0 = *(const uint4*)(m + (long)s0 * 64 + f8);
            if (g < rem) ACC8(u0);
        }
    }
#undef ACC8
    // reduce across the 8 edge subgroups (all lanes end up replicated)
#pragma unroll
    for (int off = 8; off <= 32; off <<= 1) {
        a0 += __shfl_xor(a0, off, 64); a1 += __shfl_xor(a1, off, 64);
        a2 += __shfl_xor(a2, off, 64); a3 += __shfl_xor(a3, off, 64);
        a4 += __shfl_xor(a4, off, 64); a5 += __shfl_xor(a5, off, 64);
        a6 += __shfl_xor(a6, off, 64); a7 += __shfl_xor(a7, off, 64);
    }
    // add root term + bias, relu
    const float* arow = a + (long)node * 64 + f8;
    float4 o0 = *(const float4*)arow;
    float4 o1 = *(const float4*)(arow + 4);
    a0 = fmaxf(a0 + o0.x, 0.f); a1 = fmaxf(a1 + o0.y, 0.f);
    a2 = fmaxf(a2 + o0.z, 0.f); a3 = fmaxf(a3 + o0.w, 0.f);
    a4 = fmaxf(a4 + o1.x, 0.f); a5 = fmaxf(a5 + o1.y, 0.f);
    a6 = fmaxf(a6 + o1.z, 0.f); a7 = fmaxf(a7 + o1.w, 0.f);
    if (FINAL) {
        float4 w0 = *(const float4*)(postW + f8);
        float4 w1 = *(const float4*)(postW + f8 + 4);
        float4 w2 = *(const float4*)(postW + 64 + f8);
        float4 w3 = *(const float4*)(postW + 64 + f8 + 4);
        float p0 = a0 * w0.x + a1 * w0.y + a2 * w0.z + a3 * w0.w +
                   a4 * w1.x + a5 * w1.y + a6 * w1.z + a7 * w1.w;
        float p1 = a0 * w2.x + a1 * w2.y + a2 * w2.z + a3 * w2.w +
                   a4 * w3.x + a5 * w3.y + a6 * w3.z + a7 * w3.w;
#pragma unroll
        for (int off = 1; off <= 4; off <<= 1) {
            p0 += __shfl_xor(p0, off, 64);
            p1 += __shfl_xor(p1, off, 64);
        }
        if (lane == 0) {
            out[(long)node * 2 + 0] = fmaxf(p0 + postb[0], 0.f);
            out[(long)node * 2 + 1] = fmaxf(p1 + postb[1], 0.f);
        }
    } else {
        if (g == 0) {
            float* dst = a + (long)node * 64 + f8;
            float4 r0v; r0v.x = a0; r0v.y = a1; r0v.z = a2; r0v.w = a3;
            float4 r1v; r1v.x = a4; r1v.y = a5; r1v.z = a6; r1v.w = a7;
            *(float4*)dst = r0v;
            *(float4*)(dst + 4) = r1v;
        }
    }
}

extern "C" void kernel_launch(void* const* d_in, const int* in_sizes, int n_in,
                              void* d_out, int out_size, void* d_ws, size_t ws_size,
                              hipStream_t stream) {
    const float* x = (const float*)d_in[0];
    const int* esrc = (const int*)d_in[1];
    const int* edst = esrc + N_EDGES;
    const float* preW = (const float*)d_in[2];
    const float* preb = (const float*)d_in[3];
    const float* postW = (const float*)d_in[4];
    const float* postb = (const float*)d_in[5];
    const float* relW[3] = {(const float*)d_in[6], (const float*)d_in[9], (const float*)d_in[12]};
    const float* relb[3] = {(const float*)d_in[7], (const float*)d_in[10], (const float*)d_in[13]};
    const float* rootW[3] = {(const float*)d_in[8], (const float*)d_in[11], (const float*)d_in[14]};
    float* out = (float*)d_out;

    const size_t NF = (size_t)N_NODES * HID;
    char* p = (char*)d_ws;
    float* hA = (float*)p; p += NF * 4;
    float* hB = (float*)p; p += NF * 4;
    __half* mB = (__half*)p; p += NF * 2;
    p = (char*)(((size_t)p + 255) & ~(size_t)255);
    int* rowp = (int*)p; p += (size_t)(N_NODES + 1) * 4;
    p = (char*)(((size_t)p + 255) & ~(size_t)255);
    int* ssrc = (int*)p; p += (size_t)N_EDGES * 4;
    int* bkt_off = (int*)p; p += 512 * 4;
    int* bcur = (int*)p; p += 512 * 4;
    // tmp (NBKT*CAP*4 = 9.6 MB) aliases mB (12.8 MB): CSR build finishes
    // before any gemmt writes mB.
    unsigned int* tmp = (unsigned int*)mB;

    // --- build CSR (by dst): fixed-cap bins -> scan -> per-bucket sort ---
    binit_kernel<<<1, 512, 0, stream>>>(bcur);
    bucket_kernel<<<(N_EDGES + TILE - 1) / TILE, 512, 0, stream>>>(esrc, edst, bcur, tmp);
    kscan_bkt<<<1, 512, 0, stream>>>(bcur, bkt_off, rowp);
    passb_kernel<<<NBKT, 256, 0, stream>>>(tmp, bkt_off, rowp, ssrc);

    // --- pre layer ---
    pre_kernel<<<(N_NODES * HID + 255) / 256, 256, 0, stream>>>(x, preW, preb, hA);

    const int GEMM_BLOCKS = (N_NODES + 127) / 128;  // 782
    const int GATHER_BLOCKS = (N_NODES + 3) / 4;    // 4 waves/block, wave-per-node

    // layer 0: hA -> hB
    gemmt_kernel<<<GEMM_BLOCKS, 256, 0, stream>>>(hA, relW[0], relb[0], rootW[0], mB, hB);
    gather_kernel<0><<<GATHER_BLOCKS, 256, 0, stream>>>(mB, hB, rowp, ssrc, nullptr, nullptr, nullptr);
    // layer 1: hB -> hA
    gemmt_kernel<<<GEMM_BLOCKS, 256, 0, stream>>>(hB, relW[1], relb[1], rootW[1], mB, hA);
    gather_kernel<0><<<GATHER_BLOCKS, 256, 0, stream>>>(mB, hA, rowp, ssrc, nullptr, nullptr, nullptr);
    // layer 2 + post: hA -> out
    gemmt_kernel<<<GEMM_BLOCKS, 256, 0, stream>>>(hA, relW[2], relb[2], rootW[2], mB, hB);
    gather_kernel<1><<<GATHER_BLOCKS, 256, 0, stream>>>(mB, hB, rowp, ssrc, postW, postb, out);
}

// Round 8
// 360.806 us; speedup vs baseline: 2.5232x; 1.0051x over previous
//
#include <hip/hip_runtime.h>
#include <hip/hip_fp16.h>

#define N_NODES 100000
#define N_EDGES 1600000
#define HID 64

#define BSH 8                         // bucket = dst >> 8 (256 nodes per bucket)
#define NBKT ((N_NODES + 255) / 256)  // 391
#define CAP 6144                      // fixed tmp region per bucket (mean 4093, sd 64)
#define TILE 4096                     // edges per bucket_kernel block

// h = relu(x @ preW.T + preb), x: [N,3], preW: [64,3]
__global__ void pre_kernel(const float* __restrict__ x, const float* __restrict__ W,
                           const float* __restrict__ b, float* __restrict__ h) {
    int tid = blockIdx.x * blockDim.x + threadIdx.x;
    if (tid >= N_NODES * HID) return;
    int i = tid >> 6, j = tid & 63;
    float acc = b[j];
    acc = fmaf(x[i * 3 + 0], W[j * 3 + 0], acc);
    acc = fmaf(x[i * 3 + 1], W[j * 3 + 1], acc);
    acc = fmaf(x[i * 3 + 2], W[j * 3 + 2], acc);
    h[tid] = fmaxf(acc, 0.f);
}

__global__ void binit_kernel(int* __restrict__ bcur) {
    int b = threadIdx.x;
    if (b < NBKT) bcur[b] = b * CAP;
}

// Pass A: bin edges by dst-bucket into fixed-capacity bucket regions of tmp.
// packed tmp word: (dst & 255) << 17 | src   (src < 2^17)
__global__ void __launch_bounds__(512) bucket_kernel(const int* __restrict__ src,
                                                     const int* __restrict__ dst,
                                                     int* __restrict__ bcur,
                                                     unsigned int* __restrict__ tmp) {
    __shared__ unsigned long long ed[TILE];  // 32 KB staged (dst<<32 | src)
    __shared__ int cnt[NBKT], cnt2[NBKT], scnx[NBKT], gbase[NBKT];
    __shared__ int s[512];
    int tid = threadIdx.x;
    int bstart = blockIdx.x * TILE;
    int tcnt = N_EDGES - bstart;
    if (tcnt > TILE) tcnt = TILE;
    if (tcnt < 0) tcnt = 0;
    for (int b = tid; b < NBKT; b += 512) { cnt[b] = 0; cnt2[b] = 0; }
    __syncthreads();
    for (int i = tid; i < tcnt; i += 512) atomicAdd(&cnt[dst[bstart + i] >> BSH], 1);
    __syncthreads();
    s[tid] = (tid < NBKT) ? cnt[tid] : 0;
    __syncthreads();
    for (int off = 1; off < 512; off <<= 1) {
        int add = (tid >= off) ? s[tid - off] : 0;
        __syncthreads();
        s[tid] += add;
        __syncthreads();
    }
    if (tid < NBKT) {
        scnx[tid] = s[tid] - cnt[tid];
        gbase[tid] = atomicAdd(&bcur[tid], cnt[tid]);
    }
    __syncthreads();
    for (int i = tid; i < tcnt; i += 512) {
        int e = bstart + i;
        int d = dst[e], sc = src[e];
        int b = d >> BSH;
        int pos = scnx[b] + atomicAdd(&cnt2[b], 1);
        ed[pos] = ((unsigned long long)(unsigned)d << 32) | (unsigned)sc;
    }
    __syncthreads();
    for (int i = tid; i < tcnt; i += 512) {
        unsigned long long v = ed[i];
        int d = (int)(v >> 32);
        unsigned sc = (unsigned)v;
        int b = d >> BSH;
        int idx = gbase[b] + (i - scnx[b]);
        if (idx < (b + 1) * CAP)  // statistically unreachable guard
            tmp[idx] = ((unsigned)(d & 255) << 17) | sc;
    }
}

// Scan of per-bucket counts (bcur - base) -> global bucket offsets; rowp[N]=total.
__global__ void __launch_bounds__(512) kscan_bkt(const int* __restrict__ bcur,
                                                 int* __restrict__ bkt_off,
                                                 int* __restrict__ rowp) {
    __shared__ int s[512];
    int t = threadIdx.x;
    int v = 0;
    if (t < NBKT) {
        v = bcur[t] - t * CAP;
        if (v > CAP) v = CAP;
    }
    s[t] = v;
    __syncthreads();
    for (int off = 1; off < 512; off <<= 1) {
        int a = (t >= off) ? s[t - off] : 0;
        __syncthreads();
        s[t] += a;
        __syncthreads();
    }
    if (t < NBKT) bkt_off[t] = s[t] - v;
    if (t == 511) { bkt_off[NBKT] = s[511]; rowp[N_NODES] = s[511]; }
}

// Pass B: per bucket -- node degrees in LDS, scan -> rowp, counting-sort scatter.
__global__ void __launch_bounds__(256) passb_kernel(const unsigned int* __restrict__ tmp,
                                                    const int* __restrict__ bkt_off,
                                                    int* __restrict__ rowp,
                                                    int* __restrict__ ssrc) {
    __shared__ int cnt[256], s[256], cur[256];
    int tid = threadIdx.x;
    int b = blockIdx.x;
    int lo_t = b * CAP;
    int ne = bkt_off[b + 1] - bkt_off[b];
    cnt[tid] = 0;
    __syncthreads();
    for (int i = tid; i < ne; i += 256) atomicAdd(&cnt[tmp[lo_t + i] >> 17], 1);
    __syncthreads();
    int v = cnt[tid];
    s[tid] = v;
    __syncthreads();
    for (int off = 1; off < 256; off <<= 1) {
        int a = (tid >= off) ? s[tid - off] : 0;
        __syncthreads();
        s[tid] += a;
        __syncthreads();
    }
    int excl = bkt_off[b] + s[tid] - v;
    int node = (b << BSH) + tid;
    if (node < N_NODES) rowp[node] = excl;
    cur[tid] = excl;
    __syncthreads();
    for (int i = tid; i < ne; i += 256) {
        unsigned u = tmp[lo_t + i];
        int pos = atomicAdd(&cur[u >> 17], 1);
        ssrc[pos] = (int)(u & 0x1FFFF);
    }
}

// Register-tiled dual GEMM: m = fp16(h @ relW.T), aout = h @ rootW.T + relb (fp32).
// Block tile: 128 nodes x 128 outputs (j<64 -> m, j>=64 -> aout).
// 256 threads, each 8 nodes x 8 outputs, LDS stride 68 (bank-conflict-free).
__global__ void __launch_bounds__(256) gemmt_kernel(const float* __restrict__ h,
                                                    const float* __restrict__ relW,
                                                    const float* __restrict__ relb,
                                                    const float* __restrict__ rootW,
                                                    __half* __restrict__ m,
                                                    float* __restrict__ aout) {
    __shared__ float hs[128 * 68];
    __shared__ float ws[128 * 68];
    int tid = threadIdx.x;
    int i0 = blockIdx.x * 128;
    for (int c = 0; c < 8; c++) {
        int f = tid + c * 256;            // float4 index, 2048 total
        int row = f >> 4, c4 = (f & 15) << 2;
        float4 hv = {0.f, 0.f, 0.f, 0.f};
        if (i0 + row < N_NODES) hv = *(const float4*)&h[(long)(i0 + row) * 64 + c4];
        *(float4*)&hs[row * 68 + c4] = hv;
        int j = f >> 4;
        float4 wv = (j < 64) ? *(const float4*)&relW[j * 64 + c4]
                             : *(const float4*)&rootW[(j - 64) * 64 + c4];
        *(float4*)&ws[j * 68 + c4] = wv;
    }
    int ig = tid >> 4;   // node group 0..15, nodes ig+16n
    int jg = tid & 15;   // out group 0..15,  outs  jg+16m
    float rb[4];
#pragma unroll
    for (int t = 0; t < 4; t++) rb[t] = relb[jg + 16 * t];
    float acc[8][8];
#pragma unroll
    for (int n = 0; n < 8; n++)
#pragma unroll
        for (int mm = 0; mm < 8; mm++) acc[n][mm] = 0.f;
    __syncthreads();

    for (int kk = 0; kk < 64; kk += 4) {
        float4 av[8], bv[8];
#pragma unroll
        for (int n = 0; n < 8; n++) av[n] = *(const float4*)&hs[(ig + 16 * n) * 68 + kk];
#pragma unroll
        for (int mm = 0; mm < 8; mm++) bv[mm] = *(const float4*)&ws[(jg + 16 * mm) * 68 + kk];
#pragma unroll
        for (int n = 0; n < 8; n++)
#pragma unroll
            for (int mm = 0; mm < 8; mm++) {
                acc[n][mm] = fmaf(av[n].x, bv[mm].x, acc[n][mm]);
                acc[n][mm] = fmaf(av[n].y, bv[mm].y, acc[n][mm]);
                acc[n][mm] = fmaf(av[n].z, bv[mm].z, acc[n][mm]);
                acc[n][mm] = fmaf(av[n].w, bv[mm].w, acc[n][mm]);
            }
    }
#pragma unroll
    for (int n = 0; n < 8; n++) {
        int node = i0 + ig + 16 * n;
        if (node >= N_NODES) continue;
#pragma unroll
        for (int mm = 0; mm < 4; mm++)
            m[(long)node * 64 + jg + 16 * mm] = __float2half(acc[n][mm]);
#pragma unroll
        for (int mm = 4; mm < 8; mm++)
            aout[(long)node * 64 + jg + 16 * (mm - 4)] = acc[n][mm] + rb[mm - 4];
    }
}

// fp16-m gather: wave per node; lane = (edge subgroup g = lane>>3) x
// (feature oct f8 = (lane&7)*8). Per-lane direct index loads (no cross-lane
// shuffles in the hot loop); 8 edges per uint4 data load, fp32 accumulate.
// a (root term / output h) stays fp32.
template <int FINAL>
__global__ void gather_kernel(const __half* __restrict__ m, float* __restrict__ a,
                              const int* __restrict__ rowp, const int* __restrict__ ssrc,
                              const float* __restrict__ postW, const float* __restrict__ postb,
                              float* __restrict__ out) {
    int lane = threadIdx.x & 63;
    int node = (blockIdx.x * blockDim.x + threadIdx.x) >> 6;
    if (node >= N_NODES) return;
    int g = lane >> 3;          // edge subgroup 0..7
    int f8 = (lane & 7) << 3;   // feature base 0,8,...,56
    int r0 = rowp[node], r1 = rowp[node + 1];
    int nedge = r1 - r0;
    float a0 = 0.f, a1 = 0.f, a2 = 0.f, a3 = 0.f, a4 = 0.f, a5 = 0.f, a6 = 0.f, a7 = 0.f;
#define ACC8(u)                                                         \
    {                                                                   \
        float2 f_;                                                      \
        f_ = __half22float2(*(__half2*)&(u).x); a0 += f_.x; a1 += f_.y; \
        f_ = __half22float2(*(__half2*)&(u).y); a2 += f_.x; a3 += f_.y; \
        f_ = __half22float2(*(__half2*)&(u).z); a4 += f_.x; a5 += f_.y; \
        f_ = __half22float2(*(__half2*)&(u).w); a6 += f_.x; a7 += f_.y; \
    }
    int ns = nedge >> 3;        // full octets of edges
    int q = 0;
    for (; q + 4 <= ns; q += 4) {
        int b0 = r0 + q * 8 + g;
        int s0 = ssrc[b0];
        int s1 = ssrc[b0 + 8];
        int s2 = ssrc[b0 + 16];
        int s3 = ssrc[b0 + 24];
        uint4 u0 = *(const uint4*)(m + (long)s0 * 64 + f8);
        uint4 u1 = *(const uint4*)(m + (long)s1 * 64 + f8);
        uint4 u2 = *(const uint4*)(m + (long)s2 * 64 + f8);
        uint4 u3 = *(const uint4*)(m + (long)s3 * 64 + f8);
        ACC8(u0); ACC8(u1); ACC8(u2); ACC8(u3);
    }
    for (; q + 2 <= ns; q += 2) {
        int b0 = r0 + q * 8 + g;
        int s0 = ssrc[b0];
        int s1 = ssrc[b0 + 8];
        uint4 u0 = *(const uint4*)(m + (long)s0 * 64 + f8);
        uint4 u1 = *(const uint4*)(m + (long)s1 * 64 + f8);
        ACC8(u0); ACC8(u1);
    }
    for (; q < ns; ++q) {
        int s0 = ssrc[r0 + q * 8 + g];
        uint4 u0 = *(const uint4*)(m + (long)s0 * 64 + f8);
        ACC8(u0);
    }
    int rem = nedge & 7;
    if (rem && g < rem) {
        int s0 = ssrc[r0 + ns * 8 + g];
        uint4 u0 = *(const uint4*)(m + (long)s0 * 64 + f8);
        ACC8(u0);
    }
#undef ACC8
    // reduce across the 8 edge subgroups (all lanes end up replicated)
#pragma unroll
    for (int off = 8; off <= 32; off <<= 1) {
        a0 += __shfl_xor(a0, off, 64); a1 += __shfl_xor(a1, off, 64);
        a2 += __shfl_xor(a2, off, 64); a3 += __shfl_xor(a3, off, 64);
        a4 += __shfl_xor(a4, off, 64); a5 += __shfl_xor(a5, off, 64);
        a6 += __shfl_xor(a6, off, 64); a7 += __shfl_xor(a7, off, 64);
    }
    // add root term (fp32) + relu
    const float* arow = a + (long)node * 64 + f8;
    float4 o0 = *(const float4*)arow;
    float4 o1 = *(const float4*)(arow + 4);
    a0 = fmaxf(a0 + o0.x, 0.f); a1 = fmaxf(a1 + o0.y, 0.f);
    a2 = fmaxf(a2 + o0.z, 0.f); a3 = fmaxf(a3 + o0.w, 0.f);
    a4 = fmaxf(a4 + o1.x, 0.f); a5 = fmaxf(a5 + o1.y, 0.f);
    a6 = fmaxf(a6 + o1.z, 0.f); a7 = fmaxf(a7 + o1.w, 0.f);
    if (FINAL) {
        float4 w0 = *(const float4*)(postW + f8);
        float4 w1 = *(const float4*)(postW + f8 + 4);
        float4 w2 = *(const float4*)(postW + 64 + f8);
        float4 w3 = *(const float4*)(postW + 64 + f8 + 4);
        float p0 = a0 * w0.x + a1 * w0.y + a2 * w0.z + a3 * w0.w +
                   a4 * w1.x + a5 * w1.y + a6 * w1.z + a7 * w1.w;
        float p1 = a0 * w2.x + a1 * w2.y + a2 * w2.z + a3 * w2.w +
                   a4 * w3.x + a5 * w3.y + a6 * w3.z + a7 * w3.w;
#pragma unroll
        for (int off = 1; off <= 4; off <<= 1) {
            p0 += __shfl_xor(p0, off, 64);
            p1 += __shfl_xor(p1, off, 64);
        }
        if (lane == 0) {
            out[(long)node * 2 + 0] = fmaxf(p0 + postb[0], 0.f);
            out[(long)node * 2 + 1] = fmaxf(p1 + postb[1], 0.f);
        }
    } else {
        if (g == 0) {
            float4 r0v; r0v.x = a0; r0v.y = a1; r0v.z = a2; r0v.w = a3;
            float4 r1v; r1v.x = a4; r1v.y = a5; r1v.z = a6; r1v.w = a7;
            float* dst = a + (long)node * 64 + f8;
            *(float4*)dst = r0v;
            *(float4*)(dst + 4) = r1v;
        }
    }
}

extern "C" void kernel_launch(void* const* d_in, const int* in_sizes, int n_in,
                              void* d_out, int out_size, void* d_ws, size_t ws_size,
                              hipStream_t stream) {
    const float* x = (const float*)d_in[0];
    const int* esrc = (const int*)d_in[1];
    const int* edst = esrc + N_EDGES;
    const float* preW = (const float*)d_in[2];
    const float* preb = (const float*)d_in[3];
    const float* postW = (const float*)d_in[4];
    const float* postb = (const float*)d_in[5];
    const float* relW[3] = {(const float*)d_in[6], (const float*)d_in[9], (const float*)d_in[12]};
    const float* relb[3] = {(const float*)d_in[7], (const float*)d_in[10], (const float*)d_in[13]};
    const float* rootW[3] = {(const float*)d_in[8], (const float*)d_in[11], (const float*)d_in[14]};
    float* out = (float*)d_out;

    const size_t NF = (size_t)N_NODES * HID;
    char* p = (char*)d_ws;
    float* hA = (float*)p; p += NF * 4;
    float* hB = (float*)p; p += NF * 4;
    __half* mB = (__half*)p; p += NF * 2;
    p = (char*)(((size_t)p + 255) & ~(size_t)255);
    int* rowp = (int*)p; p += (size_t)(N_NODES + 1) * 4;
    p = (char*)(((size_t)p + 255) & ~(size_t)255);
    int* ssrc = (int*)p; p += (size_t)N_EDGES * 4;
    int* bkt_off = (int*)p; p += 512 * 4;
    int* bcur = (int*)p; p += 512 * 4;
    // tmp (NBKT*CAP*4 = 9.6 MB) aliases mB (12.8 MB): CSR build finishes
    // before any gemmt writes mB.
    unsigned int* tmp = (unsigned int*)mB;

    // --- build CSR (by dst): fixed-cap bins -> scan -> per-bucket sort ---
    binit_kernel<<<1, 512, 0, stream>>>(bcur);
    bucket_kernel<<<(N_EDGES + TILE - 1) / TILE, 512, 0, stream>>>(esrc, edst, bcur, tmp);
    kscan_bkt<<<1, 512, 0, stream>>>(bcur, bkt_off, rowp);
    passb_kernel<<<NBKT, 256, 0, stream>>>(tmp, bkt_off, rowp, ssrc);

    // --- pre layer ---
    pre_kernel<<<(N_NODES * HID + 255) / 256, 256, 0, stream>>>(x, preW, preb, hA);

    const int GEMM_BLOCKS = (N_NODES + 127) / 128;  // 782
    const int GATHER_BLOCKS = (N_NODES + 3) / 4;    // 4 waves/block, wave-per-node

    // layer 0: hA -> hB
    gemmt_kernel<<<GEMM_BLOCKS, 256, 0, stream>>>(hA, relW[0], relb[0], rootW[0], mB, hB);
    gather_kernel<0><<<GATHER_BLOCKS, 256, 0, stream>>>(mB, hB, rowp, ssrc, nullptr, nullptr, nullptr);
    // layer 1: hB -> hA
    gemmt_kernel<<<GEMM_BLOCKS, 256, 0, stream>>>(hB, relW[1], relb[1], rootW[1], mB, hA);
    gather_kernel<0><<<GATHER_BLOCKS, 256, 0, stream>>>(mB, hA, rowp, ssrc, nullptr, nullptr, nullptr);
    // layer 2 + post: hA -> out
    gemmt_kernel<<<GEMM_BLOCKS, 256, 0, stream>>>(hA, relW[2], relb[2], rootW[2], mB, hB);
    gather_kernel<1><<<GATHER_BLOCKS, 256, 0, stream>>>(mB, hB, rowp, ssrc, postW, postb, out);
}

// Round 9
// 339.660 us; speedup vs baseline: 2.6802x; 1.0623x over previous
//
#include <hip/hip_runtime.h>
#include <hip/hip_fp16.h>

#define N_NODES 100000
#define N_EDGES 1600000
#define HID 64

#define BSH 8                         // bucket = dst >> 8 (256 nodes per bucket)
#define NBKT ((N_NODES + 255) / 256)  // 391
#define CAP 6144                      // fixed tmp region per bucket (mean 4093, sd 64)
#define TILE 4096                     // edges per bucket_kernel block

// h = relu(x @ preW.T + preb), x: [N,3], preW: [64,3]
__global__ void pre_kernel(const float* __restrict__ x, const float* __restrict__ W,
                           const float* __restrict__ b, float* __restrict__ h) {
    int tid = blockIdx.x * blockDim.x + threadIdx.x;
    if (tid >= N_NODES * HID) return;
    int i = tid >> 6, j = tid & 63;
    float acc = b[j];
    acc = fmaf(x[i * 3 + 0], W[j * 3 + 0], acc);
    acc = fmaf(x[i * 3 + 1], W[j * 3 + 1], acc);
    acc = fmaf(x[i * 3 + 2], W[j * 3 + 2], acc);
    h[tid] = fmaxf(acc, 0.f);
}

// Pass A: bin edges by dst-bucket into fixed-capacity bucket regions of tmp.
// bcur is a zero-initialized per-bucket counter (region base = b*CAP).
// packed tmp word: (dst & 255) << 17 | src   (src < 2^17)
__global__ void __launch_bounds__(512) bucket_kernel(const int* __restrict__ src,
                                                     const int* __restrict__ dst,
                                                     int* __restrict__ bcur,
                                                     unsigned int* __restrict__ tmp) {
    __shared__ unsigned long long ed[TILE];  // 32 KB staged (dst<<32 | src)
    __shared__ int cnt[NBKT], cnt2[NBKT], scnx[NBKT], gbase[NBKT];
    __shared__ int s[512];
    int tid = threadIdx.x;
    int bstart = blockIdx.x * TILE;
    int tcnt = N_EDGES - bstart;
    if (tcnt > TILE) tcnt = TILE;
    if (tcnt < 0) tcnt = 0;
    for (int b = tid; b < NBKT; b += 512) { cnt[b] = 0; cnt2[b] = 0; }
    __syncthreads();
    for (int i = tid; i < tcnt; i += 512) atomicAdd(&cnt[dst[bstart + i] >> BSH], 1);
    __syncthreads();
    s[tid] = (tid < NBKT) ? cnt[tid] : 0;
    __syncthreads();
    for (int off = 1; off < 512; off <<= 1) {
        int add = (tid >= off) ? s[tid - off] : 0;
        __syncthreads();
        s[tid] += add;
        __syncthreads();
    }
    if (tid < NBKT) {
        scnx[tid] = s[tid] - cnt[tid];
        gbase[tid] = tid * CAP + atomicAdd(&bcur[tid], cnt[tid]);
    }
    __syncthreads();
    for (int i = tid; i < tcnt; i += 512) {
        int e = bstart + i;
        int d = dst[e], sc = src[e];
        int b = d >> BSH;
        int pos = scnx[b] + atomicAdd(&cnt2[b], 1);
        ed[pos] = ((unsigned long long)(unsigned)d << 32) | (unsigned)sc;
    }
    __syncthreads();
    for (int i = tid; i < tcnt; i += 512) {
        unsigned long long v = ed[i];
        int d = (int)(v >> 32);
        unsigned sc = (unsigned)v;
        int b = d >> BSH;
        int idx = gbase[b] + (i - scnx[b]);
        if (idx < (b + 1) * CAP)  // statistically unreachable guard
            tmp[idx] = ((unsigned)(d & 255) << 17) | sc;
    }
}

// Scan of per-bucket counts -> global bucket offsets; rowp[N]=total.
__global__ void __launch_bounds__(512) kscan_bkt(const int* __restrict__ bcur,
                                                 int* __restrict__ bkt_off,
                                                 int* __restrict__ rowp) {
    __shared__ int s[512];
    int t = threadIdx.x;
    int v = 0;
    if (t < NBKT) {
        v = bcur[t];
        if (v > CAP) v = CAP;
    }
    s[t] = v;
    __syncthreads();
    for (int off = 1; off < 512; off <<= 1) {
        int a = (t >= off) ? s[t - off] : 0;
        __syncthreads();
        s[t] += a;
        __syncthreads();
    }
    if (t < NBKT) bkt_off[t] = s[t] - v;
    if (t == 511) { bkt_off[NBKT] = s[511]; rowp[N_NODES] = s[511]; }
}

// Pass B: per bucket -- node degrees in LDS, scan -> rowp, counting-sort scatter.
__global__ void __launch_bounds__(256) passb_kernel(const unsigned int* __restrict__ tmp,
                                                    const int* __restrict__ bkt_off,
                                                    int* __restrict__ rowp,
                                                    int* __restrict__ ssrc) {
    __shared__ int cnt[256], s[256], cur[256];
    int tid = threadIdx.x;
    int b = blockIdx.x;
    int lo_t = b * CAP;
    int ne = bkt_off[b + 1] - bkt_off[b];
    cnt[tid] = 0;
    __syncthreads();
    for (int i = tid; i < ne; i += 256) atomicAdd(&cnt[tmp[lo_t + i] >> 17], 1);
    __syncthreads();
    int v = cnt[tid];
    s[tid] = v;
    __syncthreads();
    for (int off = 1; off < 256; off <<= 1) {
        int a = (tid >= off) ? s[tid - off] : 0;
        __syncthreads();
        s[tid] += a;
        __syncthreads();
    }
    int excl = bkt_off[b] + s[tid] - v;
    int node = (b << BSH) + tid;
    if (node < N_NODES) rowp[node] = excl;
    cur[tid] = excl;
    __syncthreads();
    for (int i = tid; i < ne; i += 256) {
        unsigned u = tmp[lo_t + i];
        int pos = atomicAdd(&cur[u >> 17], 1);
        ssrc[pos] = (int)(u & 0x1FFFF);
    }
}

// Register-tiled dual GEMM: m = fp16(h @ relW.T), aout = h @ rootW.T + relb (fp32).
// Block tile: 128 nodes x 128 outputs (j<64 -> m, j>=64 -> aout).
__global__ void __launch_bounds__(256) gemmt_kernel(const float* __restrict__ h,
                                                    const float* __restrict__ relW,
                                                    const float* __restrict__ relb,
                                                    const float* __restrict__ rootW,
                                                    __half* __restrict__ m,
                                                    float* __restrict__ aout) {
    __shared__ float hs[128 * 68];
    __shared__ float ws[128 * 68];
    int tid = threadIdx.x;
    int i0 = blockIdx.x * 128;
    for (int c = 0; c < 8; c++) {
        int f = tid + c * 256;            // float4 index, 2048 total
        int row = f >> 4, c4 = (f & 15) << 2;
        float4 hv = {0.f, 0.f, 0.f, 0.f};
        if (i0 + row < N_NODES) hv = *(const float4*)&h[(long)(i0 + row) * 64 + c4];
        *(float4*)&hs[row * 68 + c4] = hv;
        int j = f >> 4;
        float4 wv = (j < 64) ? *(const float4*)&relW[j * 64 + c4]
                             : *(const float4*)&rootW[(j - 64) * 64 + c4];
        *(float4*)&ws[j * 68 + c4] = wv;
    }
    int ig = tid >> 4;   // node group 0..15, nodes ig+16n
    int jg = tid & 15;   // out group 0..15,  outs  jg+16m
    float rb[4];
#pragma unroll
    for (int t = 0; t < 4; t++) rb[t] = relb[jg + 16 * t];
    float acc[8][8];
#pragma unroll
    for (int n = 0; n < 8; n++)
#pragma unroll
        for (int mm = 0; mm < 8; mm++) acc[n][mm] = 0.f;
    __syncthreads();

    for (int kk = 0; kk < 64; kk += 4) {
        float4 av[8], bv[8];
#pragma unroll
        for (int n = 0; n < 8; n++) av[n] = *(const float4*)&hs[(ig + 16 * n) * 68 + kk];
#pragma unroll
        for (int mm = 0; mm < 8; mm++) bv[mm] = *(const float4*)&ws[(jg + 16 * mm) * 68 + kk];
#pragma unroll
        for (int n = 0; n < 8; n++)
#pragma unroll
            for (int mm = 0; mm < 8; mm++) {
                acc[n][mm] = fmaf(av[n].x, bv[mm].x, acc[n][mm]);
                acc[n][mm] = fmaf(av[n].y, bv[mm].y, acc[n][mm]);
                acc[n][mm] = fmaf(av[n].z, bv[mm].z, acc[n][mm]);
                acc[n][mm] = fmaf(av[n].w, bv[mm].w, acc[n][mm]);
            }
    }
#pragma unroll
    for (int n = 0; n < 8; n++) {
        int node = i0 + ig + 16 * n;
        if (node >= N_NODES) continue;
#pragma unroll
        for (int mm = 0; mm < 4; mm++)
            m[(long)node * 64 + jg + 16 * mm] = __float2half(acc[n][mm]);
#pragma unroll
        for (int mm = 4; mm < 8; mm++)
            aout[(long)node * 64 + jg + 16 * (mm - 4)] = acc[n][mm] + rb[mm - 4];
    }
}

// fp16-m gather, 2 nodes per wave: n = lane>>5 (node half), g = (lane>>3)&3
// (edge subgroup), f8 = (lane&7)*8 (feature oct). Per-lane direct index loads,
// 8 edges per wave-wide uint4 load instr, fp32 accumulate. Root-term load
// hoisted above the edge loop; rowp scalarized.
template <int FINAL>
__global__ void gather_kernel(const __half* __restrict__ m, float* __restrict__ a,
                              const int* __restrict__ rowp, const int* __restrict__ ssrc,
                              const float* __restrict__ postW, const float* __restrict__ postb,
                              float* __restrict__ out) {
    int lane = threadIdx.x & 63;
    int pair = (blockIdx.x * blockDim.x + threadIdx.x) >> 6;
    if (pair * 2 >= N_NODES) return;
    int n = lane >> 5;          // node half 0/1
    int g = (lane >> 3) & 3;    // edge subgroup 0..3
    int f8 = (lane & 7) << 3;   // feature base 0,8,...,56
    int pb = __builtin_amdgcn_readfirstlane(pair * 2);
    int s0 = rowp[pb], s1 = rowp[pb + 1], s2 = rowp[pb + 2];  // scalar loads
    int node = pb + n;
    int r0 = n ? s1 : s0;
    int r1 = n ? s2 : s1;
    int nedge = r1 - r0;
    // hoisted root-term load (overlaps the edge loop)
    const float* arow = a + (long)node * 64 + f8;
    float4 o0 = *(const float4*)arow;
    float4 o1 = *(const float4*)(arow + 4);
    float a0 = 0.f, a1 = 0.f, a2 = 0.f, a3 = 0.f, a4 = 0.f, a5 = 0.f, a6 = 0.f, a7 = 0.f;
#define ACC8(u)                                                         \
    {                                                                   \
        float2 f_;                                                      \
        f_ = __half22float2(*(__half2*)&(u).x); a0 += f_.x; a1 += f_.y; \
        f_ = __half22float2(*(__half2*)&(u).y); a2 += f_.x; a3 += f_.y; \
        f_ = __half22float2(*(__half2*)&(u).z); a4 += f_.x; a5 += f_.y; \
        f_ = __half22float2(*(__half2*)&(u).w); a6 += f_.x; a7 += f_.y; \
    }
    int ns = nedge >> 2;        // quads of edges (4 subgroups cover 4 edges/iter)
    int q = 0;
    for (; q + 4 <= ns; q += 4) {
        int b0 = r0 + q * 4 + g;
        int i0 = ssrc[b0];
        int i1 = ssrc[b0 + 4];
        int i2 = ssrc[b0 + 8];
        int i3 = ssrc[b0 + 12];
        uint4 u0 = *(const uint4*)(m + (long)i0 * 64 + f8);
        uint4 u1 = *(const uint4*)(m + (long)i1 * 64 + f8);
        uint4 u2 = *(const uint4*)(m + (long)i2 * 64 + f8);
        uint4 u3 = *(const uint4*)(m + (long)i3 * 64 + f8);
        ACC8(u0); ACC8(u1); ACC8(u2); ACC8(u3);
    }
    if (q + 2 <= ns) {
        int b0 = r0 + q * 4 + g;
        int i0 = ssrc[b0];
        int i1 = ssrc[b0 + 4];
        uint4 u0 = *(const uint4*)(m + (long)i0 * 64 + f8);
        uint4 u1 = *(const uint4*)(m + (long)i1 * 64 + f8);
        ACC8(u0); ACC8(u1);
        q += 2;
    }
    if (q < ns) {
        int i0 = ssrc[r0 + q * 4 + g];
        uint4 u0 = *(const uint4*)(m + (long)i0 * 64 + f8);
        ACC8(u0);
    }
    int rem = nedge & 3;
    if (rem && g < rem) {
        int i0 = ssrc[r0 + ns * 4 + g];
        uint4 u0 = *(const uint4*)(m + (long)i0 * 64 + f8);
        ACC8(u0);
    }
#undef ACC8
    // reduce across the 4 edge subgroups (stays within each 32-lane half)
#pragma unroll
    for (int off = 8; off <= 16; off <<= 1) {
        a0 += __shfl_xor(a0, off, 64); a1 += __shfl_xor(a1, off, 64);
        a2 += __shfl_xor(a2, off, 64); a3 += __shfl_xor(a3, off, 64);
        a4 += __shfl_xor(a4, off, 64); a5 += __shfl_xor(a5, off, 64);
        a6 += __shfl_xor(a6, off, 64); a7 += __shfl_xor(a7, off, 64);
    }
    // add root term (fp32) + relu
    a0 = fmaxf(a0 + o0.x, 0.f); a1 = fmaxf(a1 + o0.y, 0.f);
    a2 = fmaxf(a2 + o0.z, 0.f); a3 = fmaxf(a3 + o0.w, 0.f);
    a4 = fmaxf(a4 + o1.x, 0.f); a5 = fmaxf(a5 + o1.y, 0.f);
    a6 = fmaxf(a6 + o1.z, 0.f); a7 = fmaxf(a7 + o1.w, 0.f);
    if (FINAL) {
        float4 w0 = *(const float4*)(postW + f8);
        float4 w1 = *(const float4*)(postW + f8 + 4);
        float4 w2 = *(const float4*)(postW + 64 + f8);
        float4 w3 = *(const float4*)(postW + 64 + f8 + 4);
        float p0 = a0 * w0.x + a1 * w0.y + a2 * w0.z + a3 * w0.w +
                   a4 * w1.x + a5 * w1.y + a6 * w1.z + a7 * w1.w;
        float p1 = a0 * w2.x + a1 * w2.y + a2 * w2.z + a3 * w2.w +
                   a4 * w3.x + a5 * w3.y + a6 * w3.z + a7 * w3.w;
#pragma unroll
        for (int off = 1; off <= 4; off <<= 1) {
            p0 += __shfl_xor(p0, off, 64);
            p1 += __shfl_xor(p1, off, 64);
        }
        if ((lane & 31) == 0) {
            out[(long)node * 2 + 0] = fmaxf(p0 + postb[0], 0.f);
            out[(long)node * 2 + 1] = fmaxf(p1 + postb[1], 0.f);
        }
    } else {
        if (g == 0) {
            float4 r0v; r0v.x = a0; r0v.y = a1; r0v.z = a2; r0v.w = a3;
            float4 r1v; r1v.x = a4; r1v.y = a5; r1v.z = a6; r1v.w = a7;
            float* dst = a + (long)node * 64 + f8;
            *(float4*)dst = r0v;
            *(float4*)(dst + 4) = r1v;
        }
    }
}

extern "C" void kernel_launch(void* const* d_in, const int* in_sizes, int n_in,
                              void* d_out, int out_size, void* d_ws, size_t ws_size,
                              hipStream_t stream) {
    const float* x = (const float*)d_in[0];
    const int* esrc = (const int*)d_in[1];
    const int* edst = esrc + N_EDGES;
    const float* preW = (const float*)d_in[2];
    const float* preb = (const float*)d_in[3];
    const float* postW = (const float*)d_in[4];
    const float* postb = (const float*)d_in[5];
    const float* relW[3] = {(const float*)d_in[6], (const float*)d_in[9], (const float*)d_in[12]};
    const float* relb[3] = {(const float*)d_in[7], (const float*)d_in[10], (const float*)d_in[13]};
    const float* rootW[3] = {(const float*)d_in[8], (const float*)d_in[11], (const float*)d_in[14]};
    float* out = (float*)d_out;

    const size_t NF = (size_t)N_NODES * HID;
    char* p = (char*)d_ws;
    float* hA = (float*)p; p += NF * 4;
    float* hB = (float*)p; p += NF * 4;
    __half* mB = (__half*)p; p += NF * 2;
    p = (char*)(((size_t)p + 255) & ~(size_t)255);
    int* rowp = (int*)p; p += (size_t)(N_NODES + 1) * 4;
    p = (char*)(((size_t)p + 255) & ~(size_t)255);
    int* ssrc = (int*)p; p += (size_t)N_EDGES * 4;
    int* bkt_off = (int*)p; p += 512 * 4;
    int* bcur = (int*)p; p += 512 * 4;
    // tmp (NBKT*CAP*4 = 9.6 MB) aliases mB (12.8 MB): CSR build finishes
    // before any gemmt writes mB.
    unsigned int* tmp = (unsigned int*)mB;

    // --- build CSR (by dst): fixed-cap bins -> scan -> per-bucket sort ---
    hipMemsetAsync(bcur, 0, 512 * 4, stream);
    bucket_kernel<<<(N_EDGES + TILE - 1) / TILE, 512, 0, stream>>>(esrc, edst, bcur, tmp);
    kscan_bkt<<<1, 512, 0, stream>>>(bcur, bkt_off, rowp);
    passb_kernel<<<NBKT, 256, 0, stream>>>(tmp, bkt_off, rowp, ssrc);

    // --- pre layer ---
    pre_kernel<<<(N_NODES * HID + 255) / 256, 256, 0, stream>>>(x, preW, preb, hA);

    const int GEMM_BLOCKS = (N_NODES + 127) / 128;  // 782
    const int GATHER_BLOCKS = (N_NODES / 2 + 3) / 4;  // 2 nodes/wave, 4 waves/block

    // layer 0: hA -> hB
    gemmt_kernel<<<GEMM_BLOCKS, 256, 0, stream>>>(hA, relW[0], relb[0], rootW[0], mB, hB);
    gather_kernel<0><<<GATHER_BLOCKS, 256, 0, stream>>>(mB, hB, rowp, ssrc, nullptr, nullptr, nullptr);
    // layer 1: hB -> hA
    gemmt_kernel<<<GEMM_BLOCKS, 256, 0, stream>>>(hB, relW[1], relb[1], rootW[1], mB, hA);
    gather_kernel<0><<<GATHER_BLOCKS, 256, 0, stream>>>(mB, hA, rowp, ssrc, nullptr, nullptr, nullptr);
    // layer 2 + post: hA -> out
    gemmt_kernel<<<GEMM_BLOCKS, 256, 0, stream>>>(hA, relW[2], relb[2], rootW[2], mB, hB);
    gather_kernel<1><<<GATHER_BLOCKS, 256, 0, stream>>>(mB, hB, rowp, ssrc, postW, postb, out);
}

// Round 12
// 322.316 us; speedup vs baseline: 2.8245x; 1.0538x over previous
//
#include <hip/hip_runtime.h>
#include <hip/hip_fp16.h>

#define N_NODES 100000
#define N_EDGES 1600000
#define HID 64

#define BSH 8                         // bucket = dst >> 8 (256 nodes per bucket)
#define NBKT ((N_NODES + 255) / 256)  // 391
#define CAP 6144                      // fixed tmp region per bucket (mean 4093, sd 64)
#define TILE 4096                     // edges per bucket_kernel block

// Pass A: bin edges by dst-bucket into fixed-capacity bucket regions of tmp.
// bcur is a zero-initialized per-bucket counter (region base = b*CAP).
// packed tmp word: (dst & 255) << 17 | src   (src < 2^17)
__global__ void __launch_bounds__(512) bucket_kernel(const int* __restrict__ src,
                                                     const int* __restrict__ dst,
                                                     int* __restrict__ bcur,
                                                     unsigned int* __restrict__ tmp) {
    __shared__ unsigned long long ed[TILE];  // 32 KB staged (dst<<32 | src)
    __shared__ int cnt[NBKT], cnt2[NBKT], scnx[NBKT], gbase[NBKT];
    __shared__ int s[512];
    int tid = threadIdx.x;
    int bstart = blockIdx.x * TILE;
    int tcnt = N_EDGES - bstart;
    if (tcnt > TILE) tcnt = TILE;
    if (tcnt < 0) tcnt = 0;
    for (int b = tid; b < NBKT; b += 512) { cnt[b] = 0; cnt2[b] = 0; }
    __syncthreads();
    for (int i = tid; i < tcnt; i += 512) atomicAdd(&cnt[dst[bstart + i] >> BSH], 1);
    __syncthreads();
    s[tid] = (tid < NBKT) ? cnt[tid] : 0;
    __syncthreads();
    for (int off = 1; off < 512; off <<= 1) {
        int add = (tid >= off) ? s[tid - off] : 0;
        __syncthreads();
        s[tid] += add;
        __syncthreads();
    }
    if (tid < NBKT) {
        scnx[tid] = s[tid] - cnt[tid];
        gbase[tid] = tid * CAP + atomicAdd(&bcur[tid], cnt[tid]);
    }
    __syncthreads();
    for (int i = tid; i < tcnt; i += 512) {
        int e = bstart + i;
        int d = dst[e], sc = src[e];
        int b = d >> BSH;
        int pos = scnx[b] + atomicAdd(&cnt2[b], 1);
        ed[pos] = ((unsigned long long)(unsigned)d << 32) | (unsigned)sc;
    }
    __syncthreads();
    for (int i = tid; i < tcnt; i += 512) {
        unsigned long long v = ed[i];
        int d = (int)(v >> 32);
        unsigned sc = (unsigned)v;
        int b = d >> BSH;
        int idx = gbase[b] + (i - scnx[b]);
        if (idx < (b + 1) * CAP)  // statistically unreachable guard
            tmp[idx] = ((unsigned)(d & 255) << 17) | sc;
    }
}

// Scan of per-bucket counts -> global bucket offsets; rowp[N]=total.
__global__ void __launch_bounds__(512) kscan_bkt(const int* __restrict__ bcur,
                                                 int* __restrict__ bkt_off,
                                                 int* __restrict__ rowp) {
    __shared__ int s[512];
    int t = threadIdx.x;
    int v = 0;
    if (t < NBKT) {
        v = bcur[t];
        if (v > CAP) v = CAP;
    }
    s[t] = v;
    __syncthreads();
    for (int off = 1; off < 512; off <<= 1) {
        int a = (t >= off) ? s[t - off] : 0;
        __syncthreads();
        s[t] += a;
        __syncthreads();
    }
    if (t < NBKT) bkt_off[t] = s[t] - v;
    if (t == 511) { bkt_off[NBKT] = s[511]; rowp[N_NODES] = s[511]; }
}

// Pass B: per bucket -- node degrees in LDS, scan -> rowp, counting-sort scatter.
__global__ void __launch_bounds__(256) passb_kernel(const unsigned int* __restrict__ tmp,
                                                    const int* __restrict__ bkt_off,
                                                    int* __restrict__ rowp,
                                                    int* __restrict__ ssrc) {
    __shared__ int cnt[256], s[256], cur[256];
    int tid = threadIdx.x;
    int b = blockIdx.x;
    int lo_t = b * CAP;
    int ne = bkt_off[b + 1] - bkt_off[b];
    cnt[tid] = 0;
    __syncthreads();
    for (int i = tid; i < ne; i += 256) atomicAdd(&cnt[tmp[lo_t + i] >> 17], 1);
    __syncthreads();
    int v = cnt[tid];
    s[tid] = v;
    __syncthreads();
    for (int off = 1; off < 256; off <<= 1) {
        int a = (tid >= off) ? s[tid - off] : 0;
        __syncthreads();
        s[tid] += a;
        __syncthreads();
    }
    int excl = bkt_off[b] + s[tid] - v;
    int node = (b << BSH) + tid;
    if (node < N_NODES) rowp[node] = excl;
    cur[tid] = excl;
    __syncthreads();
    for (int i = tid; i < ne; i += 256) {
        unsigned u = tmp[lo_t + i];
        int pos = atomicAdd(&cur[u >> 17], 1);
        ssrc[pos] = (int)(u & 0x1FFFF);
    }
}

// Register-tiled dual GEMM: m = fp16(mscale * (h @ relW.T)), aout = h @ rootW.T + relb (fp32).
// mscale is a power of 2 (exact): keeps layer 1-2 m within fp16 range.
// Block tile: 128 nodes x 128 outputs (j<64 -> m, j>=64 -> aout).
// PRE=1: input is x[N,3] fp32; h tile computed in staging as relu(x@preW+preb).
// PRE=0: input is h[N,64] fp32.
// NOTE (R11 bug): xs staging MUST loop t = tid..384 step 256 — a plain
// `if (tid < 384)` with 256 threads leaves xs[256..383] uninitialized LDS,
// which is run-dependent garbage -> nondeterministic output (tripwire).
template <int PRE>
__global__ void __launch_bounds__(256) gemmt_kernel(const float* __restrict__ hx,
                                                    const float* __restrict__ preW,
                                                    const float* __restrict__ preb,
                                                    const float* __restrict__ relW,
                                                    const float* __restrict__ relb,
                                                    const float* __restrict__ rootW,
                                                    float mscale,
                                                    __half* __restrict__ m,
                                                    float* __restrict__ aout) {
    __shared__ float hs[128 * 68];
    __shared__ float ws[128 * 68];
    __shared__ float xs[PRE ? 384 : 1];
    __shared__ float pw[PRE ? 192 : 1];
    __shared__ float pbs[PRE ? 64 : 1];
    int tid = threadIdx.x;
    int i0 = blockIdx.x * 128;
    // stage weights (always)
    for (int c = 0; c < 8; c++) {
        int f = tid + c * 256;  // float4 index over 128x64
        int j = f >> 4, c4 = (f & 15) << 2;
        float4 wv = (j < 64) ? *(const float4*)&relW[j * 64 + c4]
                             : *(const float4*)&rootW[(j - 64) * 64 + c4];
        *(float4*)&ws[j * 68 + c4] = wv;
    }
    if (PRE) {
        if (tid < 192) pw[tid] = preW[tid];
        if (tid < 64) pbs[tid] = preb[tid];
        for (int t = tid; t < 384; t += 256) {  // FULL coverage of xs[0..383]
            int gi = i0 * 3 + t;
            xs[t] = (gi < N_NODES * 3) ? hx[gi] : 0.f;
        }
        __syncthreads();
        for (int c = 0; c < 32; c++) {
            int e = c * 256 + tid;
            int row = e >> 6, col = e & 63;
            float v = pbs[col];
            v = fmaf(xs[row * 3 + 0], pw[col * 3 + 0], v);
            v = fmaf(xs[row * 3 + 1], pw[col * 3 + 1], v);
            v = fmaf(xs[row * 3 + 2], pw[col * 3 + 2], v);
            hs[row * 68 + col] = fmaxf(v, 0.f);
        }
    } else {
        for (int c = 0; c < 8; c++) {
            int f = tid + c * 256;            // float4 index, 2048 total
            int row = f >> 4, c4 = (f & 15) << 2;
            float4 hv = {0.f, 0.f, 0.f, 0.f};
            if (i0 + row < N_NODES) hv = *(const float4*)&hx[(long)(i0 + row) * 64 + c4];
            *(float4*)&hs[row * 68 + c4] = hv;
        }
    }
    int ig = tid >> 4;   // node group 0..15, nodes ig+16n
    int jg = tid & 15;   // out group 0..15,  outs  jg+16m
    float rb[4];
#pragma unroll
    for (int t = 0; t < 4; t++) rb[t] = relb[jg + 16 * t];
    float acc[8][8];
#pragma unroll
    for (int n = 0; n < 8; n++)
#pragma unroll
        for (int mm = 0; mm < 8; mm++) acc[n][mm] = 0.f;
    __syncthreads();

    for (int kk = 0; kk < 64; kk += 4) {
        float4 av[8], bv[8];
#pragma unroll
        for (int n = 0; n < 8; n++) av[n] = *(const float4*)&hs[(ig + 16 * n) * 68 + kk];
#pragma unroll
        for (int mm = 0; mm < 8; mm++) bv[mm] = *(const float4*)&ws[(jg + 16 * mm) * 68 + kk];
#pragma unroll
        for (int n = 0; n < 8; n++)
#pragma unroll
            for (int mm = 0; mm < 8; mm++) {
                acc[n][mm] = fmaf(av[n].x, bv[mm].x, acc[n][mm]);
                acc[n][mm] = fmaf(av[n].y, bv[mm].y, acc[n][mm]);
                acc[n][mm] = fmaf(av[n].z, bv[mm].z, acc[n][mm]);
                acc[n][mm] = fmaf(av[n].w, bv[mm].w, acc[n][mm]);
            }
    }
#pragma unroll
    for (int n = 0; n < 8; n++) {
        int node = i0 + ig + 16 * n;
        if (node >= N_NODES) continue;
#pragma unroll
        for (int mm = 0; mm < 4; mm++)
            m[(long)node * 64 + jg + 16 * mm] = __float2half(acc[n][mm] * mscale);
#pragma unroll
        for (int mm = 4; mm < 8; mm++)
            aout[(long)node * 64 + jg + 16 * (mm - 4)] = acc[n][mm] + rb[mm - 4];
    }
}

// fp16-m gather, 4 nodes per wave: n = lane>>4 (node quarter), g = (lane>>3)&1
// (edge subgroup), f8 = (lane&7)*8 (feature oct). Per-lane direct index loads,
// fp32 accumulate; root-term load hoisted; rowp scalarized.
// aggscale = 1/mscale (power of 2, exact) undoes the fp16 range scaling.
template <int FINAL>
__global__ void gather_kernel(const __half* __restrict__ m, float* __restrict__ a,
                              const int* __restrict__ rowp, const int* __restrict__ ssrc,
                              float aggscale,
                              const float* __restrict__ postW, const float* __restrict__ postb,
                              float* __restrict__ out) {
    int lane = threadIdx.x & 63;
    int wv = (blockIdx.x * blockDim.x + threadIdx.x) >> 6;
    int pb = wv * 4;
    if (pb >= N_NODES) return;
    int n = lane >> 4;          // node quarter 0..3
    int g = (lane >> 3) & 1;    // edge subgroup 0/1
    int f8 = (lane & 7) << 3;   // feature base 0,8,...,56
    pb = __builtin_amdgcn_readfirstlane(pb);
    int q0 = rowp[pb], q1 = rowp[pb + 1], q2 = rowp[pb + 2];
    int q3 = rowp[pb + 3], q4 = rowp[pb + 4];
    int node = pb + n;
    int r0 = (n == 0) ? q0 : (n == 1) ? q1 : (n == 2) ? q2 : q3;
    int r1 = (n == 0) ? q1 : (n == 1) ? q2 : (n == 2) ? q3 : q4;
    int nedge = r1 - r0;
    // hoisted root-term load (overlaps the edge loop)
    const float* arow = a + (long)node * 64 + f8;
    float4 o0 = *(const float4*)arow;
    float4 o1 = *(const float4*)(arow + 4);
    float a0 = 0.f, a1 = 0.f, a2 = 0.f, a3 = 0.f, a4 = 0.f, a5 = 0.f, a6 = 0.f, a7 = 0.f;
#define ACC8(u)                                                         \
    {                                                                   \
        float2 f_;                                                      \
        f_ = __half22float2(*(__half2*)&(u).x); a0 += f_.x; a1 += f_.y; \
        f_ = __half22float2(*(__half2*)&(u).y); a2 += f_.x; a3 += f_.y; \
        f_ = __half22float2(*(__half2*)&(u).z); a4 += f_.x; a5 += f_.y; \
        f_ = __half22float2(*(__half2*)&(u).w); a6 += f_.x; a7 += f_.y; \
    }
    int ns = nedge >> 1;        // pairs of edges (2 subgroups cover 2 edges/iter)
    int q = 0;
    for (; q + 4 <= ns; q += 4) {
        int b0 = r0 + q * 2 + g;
        int i0 = ssrc[b0];
        int i1 = ssrc[b0 + 2];
        int i2 = ssrc[b0 + 4];
        int i3 = ssrc[b0 + 6];
        uint4 u0 = *(const uint4*)(m + (long)i0 * 64 + f8);
        uint4 u1 = *(const uint4*)(m + (long)i1 * 64 + f8);
        uint4 u2 = *(const uint4*)(m + (long)i2 * 64 + f8);
        uint4 u3 = *(const uint4*)(m + (long)i3 * 64 + f8);
        ACC8(u0); ACC8(u1); ACC8(u2); ACC8(u3);
    }
    if (q + 2 <= ns) {
        int b0 = r0 + q * 2 + g;
        int i0 = ssrc[b0];
        int i1 = ssrc[b0 + 2];
        uint4 u0 = *(const uint4*)(m + (long)i0 * 64 + f8);
        uint4 u1 = *(const uint4*)(m + (long)i1 * 64 + f8);
        ACC8(u0); ACC8(u1);
        q += 2;
    }
    if (q < ns) {
        int i0 = ssrc[r0 + q * 2 + g];
        uint4 u0 = *(const uint4*)(m + (long)i0 * 64 + f8);
        ACC8(u0);
    }
    if ((nedge & 1) && g == 0) {
        int i0 = ssrc[r0 + ns * 2];
        uint4 u0 = *(const uint4*)(m + (long)i0 * 64 + f8);
        ACC8(u0);
    }
#undef ACC8
    // reduce across the 2 edge subgroups (stays within each 16-lane node group)
    a0 += __shfl_xor(a0, 8, 64); a1 += __shfl_xor(a1, 8, 64);
    a2 += __shfl_xor(a2, 8, 64); a3 += __shfl_xor(a3, 8, 64);
    a4 += __shfl_xor(a4, 8, 64); a5 += __shfl_xor(a5, 8, 64);
    a6 += __shfl_xor(a6, 8, 64); a7 += __shfl_xor(a7, 8, 64);
    // undo fp16 range scaling (exact power-of-2)
    a0 *= aggscale; a1 *= aggscale; a2 *= aggscale; a3 *= aggscale;
    a4 *= aggscale; a5 *= aggscale; a6 *= aggscale; a7 *= aggscale;
    // add root term (fp32) + relu
    a0 = fmaxf(a0 + o0.x, 0.f); a1 = fmaxf(a1 + o0.y, 0.f);
    a2 = fmaxf(a2 + o0.z, 0.f); a3 = fmaxf(a3 + o0.w, 0.f);
    a4 = fmaxf(a4 + o1.x, 0.f); a5 = fmaxf(a5 + o1.y, 0.f);
    a6 = fmaxf(a6 + o1.z, 0.f); a7 = fmaxf(a7 + o1.w, 0.f);
    if (FINAL) {
        float4 w0 = *(const float4*)(postW + f8);
        float4 w1 = *(const float4*)(postW + f8 + 4);
        float4 w2 = *(const float4*)(postW + 64 + f8);
        float4 w3 = *(const float4*)(postW + 64 + f8 + 4);
        float p0 = a0 * w0.x + a1 * w0.y + a2 * w0.z + a3 * w0.w +
                   a4 * w1.x + a5 * w1.y + a6 * w1.z + a7 * w1.w;
        float p1 = a0 * w2.x + a1 * w2.y + a2 * w2.z + a3 * w2.w +
                   a4 * w3.x + a5 * w3.y + a6 * w3.z + a7 * w3.w;
#pragma unroll
        for (int off = 1; off <= 4; off <<= 1) {
            p0 += __shfl_xor(p0, off, 64);
            p1 += __shfl_xor(p1, off, 64);
        }
        if ((lane & 15) == 0) {
            out[(long)node * 2 + 0] = fmaxf(p0 + postb[0], 0.f);
            out[(long)node * 2 + 1] = fmaxf(p1 + postb[1], 0.f);
        }
    } else {
        if (g == 0) {
            float4 r0v; r0v.x = a0; r0v.y = a1; r0v.z = a2; r0v.w = a3;
            float4 r1v; r1v.x = a4; r1v.y = a5; r1v.z = a6; r1v.w = a7;
            float* dst = a + (long)node * 64 + f8;
            *(float4*)dst = r0v;
            *(float4*)(dst + 4) = r1v;
        }
    }
}

extern "C" void kernel_launch(void* const* d_in, const int* in_sizes, int n_in,
                              void* d_out, int out_size, void* d_ws, size_t ws_size,
                              hipStream_t stream) {
    const float* x = (const float*)d_in[0];
    const int* esrc = (const int*)d_in[1];
    const int* edst = esrc + N_EDGES;
    const float* preW = (const float*)d_in[2];
    const float* preb = (const float*)d_in[3];
    const float* postW = (const float*)d_in[4];
    const float* postb = (const float*)d_in[5];
    const float* relW[3] = {(const float*)d_in[6], (const float*)d_in[9], (const float*)d_in[12]};
    const float* relb[3] = {(const float*)d_in[7], (const float*)d_in[10], (const float*)d_in[13]};
    const float* rootW[3] = {(const float*)d_in[8], (const float*)d_in[11], (const float*)d_in[14]};
    float* out = (float*)d_out;

    const size_t NF = (size_t)N_NODES * HID;
    char* p = (char*)d_ws;
    float* hA = (float*)p; p += NF * 4;
    float* hB = (float*)p; p += NF * 4;
    __half* mB = (__half*)p; p += NF * 2;
    p = (char*)(((size_t)p + 255) & ~(size_t)255);
    int* rowp = (int*)p; p += (size_t)(N_NODES + 1) * 4;
    p = (char*)(((size_t)p + 255) & ~(size_t)255);
    int* ssrc = (int*)p; p += (size_t)N_EDGES * 4;
    int* bkt_off = (int*)p; p += 512 * 4;
    int* bcur = (int*)p; p += 512 * 4;
    // tmp (NBKT*CAP*4 = 9.6 MB) aliases mB (12.8 MB): CSR build finishes
    // before any gemmt writes mB.
    unsigned int* tmp = (unsigned int*)mB;

    // --- build CSR (by dst): fixed-cap bins -> scan -> per-bucket sort ---
    hipMemsetAsync(bcur, 0, 512 * 4, stream);
    bucket_kernel<<<(N_EDGES + TILE - 1) / TILE, 512, 0, stream>>>(esrc, edst, bcur, tmp);
    kscan_bkt<<<1, 512, 0, stream>>>(bcur, bkt_off, rowp);
    passb_kernel<<<NBKT, 256, 0, stream>>>(tmp, bkt_off, rowp, ssrc);

    const int GEMM_BLOCKS = (N_NODES + 127) / 128;      // 782
    const int GATHER_BLOCKS = N_NODES / 16;             // 4 nodes/wave, 4 waves/block

    const float S1 = 1.0f / 64.0f, IS1 = 64.0f;  // layers 1-2 fp16 range scaling

    // layer 0 (pre fused): x -> mB, hB(aout); m values ~O(1), no scaling
    gemmt_kernel<1><<<GEMM_BLOCKS, 256, 0, stream>>>(x, preW, preb, relW[0], relb[0],
                                                     rootW[0], 1.0f, mB, hB);
    gather_kernel<0><<<GATHER_BLOCKS, 256, 0, stream>>>(mB, hB, rowp, ssrc, 1.0f,
                                                        nullptr, nullptr, nullptr);
    // layer 1: hB -> mB, hA(aout)
    gemmt_kernel<0><<<GEMM_BLOCKS, 256, 0, stream>>>(hB, nullptr, nullptr, relW[1], relb[1],
                                                     rootW[1], S1, mB, hA);
    gather_kernel<0><<<GATHER_BLOCKS, 256, 0, stream>>>(mB, hA, rowp, ssrc, IS1,
                                                        nullptr, nullptr, nullptr);
    // layer 2 + post: hA -> out
    gemmt_kernel<0><<<GEMM_BLOCKS, 256, 0, stream>>>(hA, nullptr, nullptr, relW[2], relb[2],
                                                     rootW[2], S1, mB, hB);
    gather_kernel<1><<<GATHER_BLOCKS, 256, 0, stream>>>(mB, hB, rowp, ssrc, IS1,
                                                        postW, postb, out);
}